// Round 10
// baseline (263.839 us; speedup 1.0000x reference)
//
#include <hip/hip_runtime.h>
#include <math.h>

#define DD    768
#define NQ    400
#define NROWS 408          // 400 q rows + 8 m_proj rows
#define JD    6144         // J*D = 8*768
#define WSLICE 4718592     // I*D*E = 8*768*768 (stride between j slices of W)
#define EPSF  1e-8f
#define K2    2304         // effective split-bf16 K (3 segments of 768)
#define K2S   1536         // stored K (hi|lo, dedup'd)

// ---------------- workspace layout (floats) ----------------
#define OFF_H     0                       // [408][6144]
#define OFF_HM    (OFF_H + 408*6144)      // [64][768]  (j*8+i major)
#define OFF_MU    (OFF_HM + 64*768)       // [64]
#define OFF_MC2   (OFF_MU + 64)           // [64]
#define OFF_G     (OFF_MC2 + 64)          // [64][8]  Gram
#define OFF_A2    (OFF_G + 512)           // [512][1536] bf16 (as u16)
#define OFF_B2    (OFF_A2 + 512*K2S/2)    // [6144][1536] bf16 (as u16)

#define FOR8(M) M(0) M(1) M(2) M(3) M(4) M(5) M(6) M(7)

typedef __attribute__((ext_vector_type(8))) short short8v;
typedef __attribute__((ext_vector_type(4))) float float4v;

__device__ inline unsigned short f2bf(float x) {
    unsigned u = __float_as_uint(x);
    u += 0x7FFF + ((u >> 16) & 1);
    return (unsigned short)(u >> 16);
}
__device__ inline float bf2f(unsigned short h) {
    return __uint_as_float(((unsigned)h) << 16);
}

// ---------------- kernel 1: pack A'=[hi|lo] and B'=[hi|lo] --------------------
__global__ __launch_bounds__(256) void k_cvt(const float* __restrict__ q,
                                             const float* __restrict__ m,
                                             const float* __restrict__ Wn,
                                             const float* __restrict__ W,
                                             unsigned short* __restrict__ A2,
                                             unsigned short* __restrict__ B2)
{
    const int bid = blockIdx.x;
    const int tid = threadIdx.x;
    if (bid < 408) {
        const int r = bid;
        unsigned short* dst = A2 + (size_t)r * K2S;
        if (r < NQ) {
            const float* src = q + (size_t)r * DD;
            #pragma unroll
            for (int u0 = 0; u0 < 3; ++u0) {
                const int u = u0 * 256 + tid;
                float x = src[u];
                unsigned short hi = f2bf(x);
                unsigned short lo = f2bf(x - bf2f(hi));
                dst[u] = hi; dst[DD + u] = lo;
            }
        } else {
            const int i = r - NQ;
            float a0 = 0.f, a1 = 0.f, a2 = 0.f;
            #pragma unroll 8
            for (int e = 0; e < DD; ++e) {
                const float mv = m[i*DD + e];
                const float* wr = Wn + (size_t)e * DD;
                a0 += mv * wr[tid];
                a1 += mv * wr[tid + 256];
                a2 += mv * wr[tid + 512];
            }
            #pragma unroll
            for (int u0 = 0; u0 < 3; ++u0) {
                const int u = u0 * 256 + tid;
                float x = (u0 == 0) ? a0 : (u0 == 1) ? a1 : a2;
                unsigned short hi = f2bf(x);
                unsigned short lo = f2bf(x - bf2f(hi));
                dst[u] = hi; dst[DD + u] = lo;
            }
        }
    } else {
        const int r0 = (bid - 408) * 4;
        #pragma unroll
        for (int rr = 0; rr < 4; ++rr) {
            const int rw = r0 + rr;
            const int jj = rw / 768;
            const int d  = rw - jj * 768;
            const float* src = W + (size_t)jj * WSLICE + (size_t)d * DD;
            unsigned short* dst = B2 + (size_t)rw * K2S;
            #pragma unroll
            for (int u0 = 0; u0 < 3; ++u0) {
                const int u = u0 * 256 + tid;
                float x = src[u];
                unsigned short hi = f2bf(x);
                unsigned short lo = f2bf(x - bf2f(hi));
                dst[u] = hi; dst[DD + u] = lo;
            }
        }
    }
}

// ---------------- kernel 2: MFMA GEMM, BM=128 x BN=64, 2-phase dbuf -----------
__global__ __launch_bounds__(256) void k_gemm_mfma(const unsigned short* __restrict__ A2,
                                                   const unsigned short* __restrict__ B2,
                                                   float* __restrict__ H)
{
    __shared__ __align__(16) unsigned short lds[2][12288];  // A:[0,8192) B:[8192,12288)
    const int tid = threadIdx.x;
    const int wv  = tid >> 6;
    const int ln  = tid & 63;
    const int c0  = blockIdx.x * 64;
    const int m0  = blockIdx.y * 128;
    const int wm  = (wv >> 1) * 64;
    const int wn  = (wv & 1) * 32;
    const unsigned short* Ap = A2 + (size_t)m0 * K2S;
    const unsigned short* Bp = B2 + (size_t)c0 * K2S;

    float4v acc[4][2];
    #pragma unroll
    for (int a = 0; a < 4; ++a)
        #pragma unroll
        for (int b = 0; b < 2; ++b)
            acc[a][b] = (float4v){0.f, 0.f, 0.f, 0.f};

#define STAGE(buf, ka, kb) {                                                      \
    _Pragma("unroll")                                                             \
    for (int qq = 0; qq < 4; ++qq) {                                              \
        const int idx = (qq << 8) + tid;                                          \
        const int row = idx >> 3;                                                 \
        const int ce  = ((idx & 7) ^ (row & 7)) << 3;                             \
        __builtin_amdgcn_global_load_lds(                                         \
            (const __attribute__((address_space(1))) void*)(Ap + (size_t)row * K2S + (ka) + ce), \
            (__attribute__((address_space(3))) void*)(&lds[buf][idx * 8]), 16, 0, 0);            \
    }                                                                             \
    _Pragma("unroll")                                                             \
    for (int qq = 0; qq < 2; ++qq) {                                              \
        const int idx = (qq << 8) + tid;                                          \
        const int row = idx >> 3;                                                 \
        const int ce  = ((idx & 7) ^ (row & 7)) << 3;                             \
        __builtin_amdgcn_global_load_lds(                                         \
            (const __attribute__((address_space(1))) void*)(Bp + (size_t)row * K2S + (kb) + ce), \
            (__attribute__((address_space(3))) void*)(&lds[buf][8192 + idx * 8]), 16, 0, 0);     \
    } }

#define COMPUTE(buf) { _Pragma("unroll")                                          \
    for (int s = 0; s < 2; ++s) {                                                 \
        short8v af[4], bf[2];                                                     \
        _Pragma("unroll")                                                         \
        for (int mi = 0; mi < 4; ++mi) {                                          \
            const int row = wm + mi * 16 + (ln & 15);                             \
            const int off = row * 64 + ((s * 32 + ((ln >> 4) * 8)) ^ ((row & 7) << 3)); \
            af[mi] = *reinterpret_cast<const short8v*>(&lds[buf][off]);           \
        }                                                                         \
        _Pragma("unroll")                                                         \
        for (int ni = 0; ni < 2; ++ni) {                                          \
            const int row = wn + ni * 16 + (ln & 15);                             \
            const int off = row * 64 + ((s * 32 + ((ln >> 4) * 8)) ^ ((row & 7) << 3)); \
            bf[ni] = *reinterpret_cast<const short8v*>(&lds[buf][8192 + off]);    \
        }                                                                         \
        _Pragma("unroll")                                                         \
        for (int mi = 0; mi < 4; ++mi)                                            \
            _Pragma("unroll")                                                     \
            for (int ni = 0; ni < 2; ++ni)                                        \
                acc[mi][ni] = __builtin_amdgcn_mfma_f32_16x16x32_bf16(af[mi], bf[ni], acc[mi][ni], 0, 0, 0); \
    } }

    STAGE(0, 0, 0);
    __syncthreads();
    int cur = 0;
    for (int k0 = 64; k0 < K2; k0 += 64) {
        const int ka = (k0 < 1536) ? k0 : k0 - 1536;   // hi | lo | hi
        const int kb = (k0 < 768)  ? k0 : k0 - 768;    // hi | hi | lo
        STAGE(cur ^ 1, ka, kb);
        COMPUTE(cur);
        __syncthreads();
        cur ^= 1;
    }
    COMPUTE(cur);
#undef STAGE
#undef COMPUTE

    #pragma unroll
    for (int mi = 0; mi < 4; ++mi) {
        #pragma unroll
        for (int r = 0; r < 4; ++r) {
            const int gr = m0 + wm + mi * 16 + (ln >> 4) * 4 + r;
            if (gr < NROWS) {
                #pragma unroll
                for (int ni = 0; ni < 2; ++ni)
                    H[(size_t)gr * JD + c0 + wn + ni * 16 + (ln & 15)] = acc[mi][ni][r];
            }
        }
    }
}

// ---------------- kernel 3: merged prep / gram (dots moved into route2) -------
__global__ __launch_bounds__(256) void k_mid(const float* __restrict__ H,
                                             const float* __restrict__ b,
                                             float* __restrict__ hm,
                                             float* __restrict__ muM,
                                             float* __restrict__ mc2M,
                                             float* __restrict__ G)
{
    const int bid = blockIdx.x;
    const int tid = threadIdx.x;
    const int lane = tid & 63, wave = tid >> 6;
    __shared__ float scr[8][4];
    __shared__ float smu;

    if (bid < 64) {
        // ---------------- prep ----------------
        const int ji = bid;
        const int j = ji >> 3, i = ji & 7;
        float vals[3];
        float s = 0.f;
        #pragma unroll
        for (int u = 0; u < 3; ++u) {
            const int d = u * 256 + tid;
            float x = H[(size_t)(NQ + i) * JD + j * DD + d] + b[(size_t)ji * DD + d];
            hm[(size_t)ji * DD + d] = x;
            vals[u] = x;
            s += x;
        }
        #pragma unroll
        for (int off = 32; off; off >>= 1) s += __shfl_down(s, off);
        if (lane == 0) scr[0][wave] = s;
        __syncthreads();
        if (tid == 0) smu = (scr[0][0] + scr[0][1] + scr[0][2] + scr[0][3]) * (1.f / 768.f);
        __syncthreads();
        const float mu = smu;
        float s2 = 0.f;
        #pragma unroll
        for (int u = 0; u < 3; ++u) { float c = vals[u] - mu; s2 += c * c; }
        __syncthreads();
        #pragma unroll
        for (int off = 32; off; off >>= 1) s2 += __shfl_down(s2, off);
        if (lane == 0) scr[0][wave] = s2;
        __syncthreads();
        if (tid == 0) { muM[ji] = mu; mc2M[ji] = scr[0][0] + scr[0][1] + scr[0][2] + scr[0][3]; }
    } else {
        // ---------------- gram ----------------
        const int ji = bid - 64;
        const int j = ji >> 3, i = ji & 7;
        const float* Hj = H + j * DD;
        const float* bj = b + (size_t)(j * 8) * DD;
        const float a0 = Hj[(size_t)(NQ + i) * JD + tid]       + bj[(size_t)i * DD + tid];
        const float a1 = Hj[(size_t)(NQ + i) * JD + 256 + tid] + bj[(size_t)i * DD + 256 + tid];
        const float a2 = Hj[(size_t)(NQ + i) * JD + 512 + tid] + bj[(size_t)i * DD + 512 + tid];
#define GDOT(k) { const float* Hp = Hj + (size_t)(NQ + k) * JD + tid;            \
        const float* bp = bj + (size_t)k * DD + tid;                             \
        float acc = a0*(Hp[0]+bp[0]) + a1*(Hp[256]+bp[256]) + a2*(Hp[512]+bp[512]); \
        acc += __shfl_down(acc, 32); acc += __shfl_down(acc, 16);                \
        acc += __shfl_down(acc, 8);  acc += __shfl_down(acc, 4);                 \
        acc += __shfl_down(acc, 2);  acc += __shfl_down(acc, 1);                 \
        if (lane == 0) scr[k][wave] = acc; }
        FOR8(GDOT)
#undef GDOT
        __syncthreads();
        if (tid < 8) G[ji*8 + tid] = scr[tid][0] + scr[tid][1] + scr[tid][2] + scr[tid][3];
    }
}

// ---------------- kernel 4: fused routing (inline dots, full unroll, 1 blk/CU) -
__global__ __launch_bounds__(768, 3) void k_route2(const float* __restrict__ H,
                                                   const float* __restrict__ hm,
                                                   const float* __restrict__ muM,
                                                   const float* __restrict__ mc2M,
                                                   const float* __restrict__ G,
                                                   float* __restrict__ out)
{
    const int n = blockIdx.x;
    const int tid = threadIdx.x;                  // d
    const int lane = tid & 63, wave = tid >> 6;   // 12 waves
    __shared__ __align__(16) float sVv[8][768];
    __shared__ float scr[24][12];
    __shared__ float rstat[24];
    __shared__ float sDot[64];
    __shared__ float sP[64], sC1[64], sC2[64], sB1[64];

#define WRED(val, idx) { float _v = (val);                           \
    _v += __shfl_down(_v, 32); _v += __shfl_down(_v, 16);            \
    _v += __shfl_down(_v, 8);  _v += __shfl_down(_v, 4);             \
    _v += __shfl_down(_v, 2);  _v += __shfl_down(_v, 1);             \
    if (lane == 0) scr[(idx)][wave] = _v; }

#define FIN(nv) { if (tid < (nv)) { float _s = 0.f;                  \
    _Pragma("unroll")                                                \
    for (int _w = 0; _w < 12; ++_w) _s += scr[tid][_w];              \
    rstat[tid] = _s; } }

#define DOTLOOP() for (int t = wave; t < 64; t += 12) {              \
        const int _j = t >> 3;                                       \
        const float* Mrow = hm + (size_t)t * DD;                     \
        float acc = 0.f;                                             \
        _Pragma("unroll")                                            \
        for (int c = 0; c < 3; ++c) {                                \
            const int dd = c * 256 + lane * 4;                       \
            const float4 mv = *reinterpret_cast<const float4*>(Mrow + dd);       \
            const float4 vv = *reinterpret_cast<const float4*>(&sVv[_j][dd]);    \
            acc += mv.x*vv.x + mv.y*vv.y + mv.z*vv.z + mv.w*vv.w;    \
        }                                                            \
        acc += __shfl_down(acc, 32); acc += __shfl_down(acc, 16);    \
        acc += __shfl_down(acc, 8);  acc += __shfl_down(acc, 4);     \
        acc += __shfl_down(acc, 2);  acc += __shfl_down(acc, 1);     \
        if (lane == 0) sDot[t] = acc;                                \
    }

#define XR3(v) { v += __shfl_xor(v, 1); v += __shfl_xor(v, 2); v += __shfl_xor(v, 4); }

    // ---- phase A: load tq0, stage in LDS, stats + inline dots (M . tq0) ----
    const float* Hn = H + (size_t)n * JD + tid;
    const float* hmp = hm + tid;
#define DECL(k) float t0_##k = Hn[k * DD]; sVv[k][tid] = t0_##k; float tq1_##k, vh_##k;
    FOR8(DECL)
#undef DECL
#define STAT0(k) WRED(t0_##k, k); WRED(t0_##k * t0_##k, 8 + k);
    FOR8(STAT0)
#undef STAT0
    __syncthreads();
    DOTLOOP();                                     // sDot = M . tq0
    FIN(16);                                       // rstat[0..7]=Sq, [8..15]=Sq2
    __syncthreads();

    // ---- stage 0 (wave 0): coefficient-space routing iteration 1 ----
    float w0 = 0.f, s1 = 0.f, dotM1 = 0.f, Sq1 = 0.f, Sq21 = 0.f, mu = 0.f, mc2 = 0.f;
    if (tid < 64) {
        const int j = lane >> 3;
        mu  = muM[lane];
        mc2 = mc2M[lane];
        const float smR = 768.f * mu;              // sum of M row
        const float dq  = sDot[lane];
        const float Sq  = rstat[j];
        const float Sq2v = rstat[8 + j];
        {
            float num  = dq - mu * Sq;
            float varq = fmaxf(Sq2v - Sq * Sq * (1.f / 768.f), 0.f);
            float den  = sqrtf(mc2 * varq) + EPSF;
            w0 = tanhf(num / den) + 0.125f;        // w0 = 1/8 + p0
        }
        const float* Gr = G + lane * 8;
        const int base = lane & ~7;
        float gw = 0.f;
        #pragma unroll
        for (int ii = 0; ii < 8; ++ii) gw += Gr[ii] * __shfl(w0, base + ii);
        float n2h1 = w0 * gw;  XR3(n2h1);          // |hv1|^2
        float dqh1 = w0 * dq;  XR3(dqh1);          // dot(q', hv1)
        float Sh1  = w0 * smR; XR3(Sh1);           // sum(hv1)
        s1 = n2h1 / ((1.f + n2h1) * sqrtf(n2h1 + EPSF));
        float c1 = s1 * gw;
        sC1[lane] = c1;
        sB1[lane] = 0.5f * s1 * w0;
        dotM1 = 0.5f * (dq + c1);
        Sq1   = 0.5f * (Sq + s1 * Sh1);
        Sq21  = 0.25f * (Sq2v + 2.f * s1 * dqh1 + s1 * s1 * n2h1);   // |tq1|^2
        float varq1 = fmaxf(Sq21 - Sq1 * Sq1 * (1.f / 768.f), 0.f);
        sP[lane] = tanhf((dotM1 - mu * Sq1) / (sqrtf(mc2 * varq1) + EPSF));  // p1
    }
    __syncthreads();

    // ---- pass 1 (d-space): hv2 + tq1 reconstruction, fully unrolled ----
#define INIT1(k) tq1_##k = 0.5f * t0_##k; vh_##k = 0.f;
    FOR8(INIT1)
#undef INIT1
    #pragma unroll
    for (int i = 0; i < 8; ++i) {
#define XA(k) float x##k = t0_##k * sC1[k * 8 + i];
        FOR8(XA)
#undef XA
        float mx = fmaxf(fmaxf(fmaxf(x0, x1), fmaxf(x2, x3)),
                         fmaxf(fmaxf(x4, x5), fmaxf(x6, x7)));
#define XE(k) x##k = __expf(x##k - mx);
        FOR8(XE)
#undef XE
        float inv = 1.f / (x0 + x1 + x2 + x3 + x4 + x5 + x6 + x7);
#define XACC(k) { const float mval = hmp[(size_t)(k * 8 + i) * DD];  \
        vh_##k  += (x##k * inv + sP[k * 8 + i]) * mval;              \
        tq1_##k += sB1[k * 8 + i] * mval; }
        FOR8(XACC)
#undef XACC
    }
#define STG(k) sVv[k][tid] = vh_##k;                                 \
    WRED(vh_##k * vh_##k, k); WRED(vh_##k, 8 + k); WRED(t0_##k * vh_##k, 16 + k);
    FOR8(STG)
#undef STG
    __syncthreads();
    // ---- pass 2: u[ji] = M_ji . hv2_j ----
    DOTLOOP();
    FIN(24);
    __syncthreads();

    // ---- stage 2 (wave 0): p2, c2 ----
    if (tid < 64) {
        const int j = lane >> 3;
        const float n2h2 = rstat[j];               // |hv2|^2
        const float Sh2  = rstat[8 + j];           // sum(hv2)
        const float dqh2 = rstat[16 + j];          // dot(q', hv2)
        const float u = sDot[lane];                // dot(M_ji, hv2_j)
        float s2 = n2h2 / ((1.f + n2h2) * sqrtf(n2h2 + EPSF));
        float c2 = s2 * u;
        sC2[lane] = c2;
        float dotM2 = 0.5f * (dotM1 + c2);
        float w0u = w0 * u; XR3(w0u);              // dot(hv1, hv2)
        float dt1h2 = 0.5f * (dqh2 + s1 * w0u);    // dot(tq1, hv2)
        float Sq2_ = 0.5f * (Sq1 + s2 * Sh2);
        float Sq22 = 0.25f * Sq21 + 0.5f * s2 * dt1h2 + 0.25f * s2 * s2 * n2h2;  // |tq2|^2
        float varq2 = fmaxf(Sq22 - Sq2_ * Sq2_ * (1.f / 768.f), 0.f);
        sP[lane] = tanhf((dotM2 - mu * Sq2_) / (sqrtf(mc2 * varq2) + EPSF));     // p2
    }
    __syncthreads();

    // ---- pass 3 (d-space): final softmax + hv3 + squash + write ----
#define ZV(k) vh_##k = 0.f;
    FOR8(ZV)
#undef ZV
    #pragma unroll
    for (int i = 0; i < 8; ++i) {
#define XA(k) float x##k = t0_##k * sC1[k * 8 + i] + tq1_##k * sC2[k * 8 + i];
        FOR8(XA)
#undef XA
        float mx = fmaxf(fmaxf(fmaxf(x0, x1), fmaxf(x2, x3)),
                         fmaxf(fmaxf(x4, x5), fmaxf(x6, x7)));
#define XE(k) x##k = __expf(x##k - mx);
        FOR8(XE)
#undef XE
        float inv = 1.f / (x0 + x1 + x2 + x3 + x4 + x5 + x6 + x7);
#define XACC(k) vh_##k += (x##k * inv + sP[k * 8 + i]) * hmp[(size_t)(k * 8 + i) * DD];
        FOR8(XACC)
#undef XACC
    }
#define NRM(k) WRED(vh_##k * vh_##k, k);
    FOR8(NRM)
#undef NRM
    __syncthreads();
    FIN(8);
    __syncthreads();
    float* On = out + (size_t)n * JD + tid;
#define WOUT(k) { float n2 = rstat[k];                               \
        float sc = n2 / ((1.f + n2) * sqrtf(n2 + EPSF));             \
        On[k * DD] = vh_##k * sc; }
    FOR8(WOUT)
#undef WOUT
#undef WRED
#undef FIN
#undef DOTLOOP
#undef XR3
}

extern "C" void kernel_launch(void* const* d_in, const int* in_sizes, int n_in,
                              void* d_out, int out_size, void* d_ws, size_t ws_size,
                              hipStream_t stream) {
    const float* m  = (const float*)d_in[0];   // [8,768]
    const float* q  = (const float*)d_in[1];   // [400,768]
    const float* W  = (const float*)d_in[2];   // [1,8,8,768,768]
    const float* b  = (const float*)d_in[3];   // [1,8,8,768]
    const float* Wn = (const float*)d_in[4];   // [768,768]
    float* out = (float*)d_out;
    float* ws  = (float*)d_ws;

    float* H     = ws + OFF_H;
    float* hm    = ws + OFF_HM;
    float* muM   = ws + OFF_MU;
    float* mc2M  = ws + OFF_MC2;
    float* G     = ws + OFF_G;
    unsigned short* A2 = (unsigned short*)(ws + OFF_A2);
    unsigned short* B2 = (unsigned short*)(ws + OFF_B2);

    k_cvt<<<dim3(1944), 256, 0, stream>>>(q, m, Wn, W, A2, B2);
    k_gemm_mfma<<<dim3(96, 4), 256, 0, stream>>>(A2, B2, H);
    k_mid<<<dim3(128), 256, 0, stream>>>(H, b, hm, muM, mc2M, G);
    k_route2<<<dim3(400), 768, 0, stream>>>(H, hm, muM, mc2M, G, out);
}

// Round 11
// 142.561 us; speedup vs baseline: 1.8507x; 1.8507x over previous
//
#include <hip/hip_runtime.h>
#include <math.h>

#define DD    768
#define NQ    400
#define NROWS 408          // 400 q rows + 8 m_proj rows
#define JD    6144         // J*D = 8*768
#define WSLICE 4718592     // I*D*E = 8*768*768 (stride between j slices of W)
#define EPSF  1e-8f
#define K2    2304         // effective split-bf16 K (3 segments of 768)
#define K2S   1536         // stored K (hi|lo, dedup'd)

// ---------------- workspace layout (floats) ----------------
#define OFF_H     0                       // [408][6144]
#define OFF_HM    (OFF_H + 408*6144)      // [64][768]  (j*8+i major)
#define OFF_MU    (OFF_HM + 64*768)       // [64]
#define OFF_MC2   (OFF_MU + 64)           // [64]
#define OFF_G     (OFF_MC2 + 64)          // [64][8]  Gram
#define OFF_DMQ   (OFF_G + 512)           // [400][64] dot(M_ji, q'_nj)
#define OFF_SQ0   (OFF_DMQ + 400*64)      // [400][8]  sum(q'_nj)
#define OFF_SQ20  (OFF_SQ0 + 400*8)       // [400][8]  sumsq(q'_nj)
#define OFF_A2    (OFF_SQ20 + 400*8)      // [512][1536] bf16 (as u16)
#define OFF_B2    (OFF_A2 + 512*K2S/2)    // [6144][1536] bf16 (as u16)

#define FOR8(M) M(0) M(1) M(2) M(3) M(4) M(5) M(6) M(7)

typedef __attribute__((ext_vector_type(8))) short short8v;
typedef __attribute__((ext_vector_type(4))) float float4v;

__device__ inline unsigned short f2bf(float x) {
    unsigned u = __float_as_uint(x);
    u += 0x7FFF + ((u >> 16) & 1);
    return (unsigned short)(u >> 16);
}
__device__ inline float bf2f(unsigned short h) {
    return __uint_as_float(((unsigned)h) << 16);
}

// ---------------- kernel 1: pack A'=[hi|lo] and B'=[hi|lo] --------------------
__global__ __launch_bounds__(256) void k_cvt(const float* __restrict__ q,
                                             const float* __restrict__ m,
                                             const float* __restrict__ Wn,
                                             const float* __restrict__ W,
                                             unsigned short* __restrict__ A2,
                                             unsigned short* __restrict__ B2)
{
    const int bid = blockIdx.x;
    const int tid = threadIdx.x;
    if (bid < 408) {
        const int r = bid;
        unsigned short* dst = A2 + (size_t)r * K2S;
        if (r < NQ) {
            const float* src = q + (size_t)r * DD;
            #pragma unroll
            for (int u0 = 0; u0 < 3; ++u0) {
                const int u = u0 * 256 + tid;
                float x = src[u];
                unsigned short hi = f2bf(x);
                unsigned short lo = f2bf(x - bf2f(hi));
                dst[u] = hi; dst[DD + u] = lo;
            }
        } else {
            const int i = r - NQ;
            float a0 = 0.f, a1 = 0.f, a2 = 0.f;
            #pragma unroll 8
            for (int e = 0; e < DD; ++e) {
                const float mv = m[i*DD + e];
                const float* wr = Wn + (size_t)e * DD;
                a0 += mv * wr[tid];
                a1 += mv * wr[tid + 256];
                a2 += mv * wr[tid + 512];
            }
            #pragma unroll
            for (int u0 = 0; u0 < 3; ++u0) {
                const int u = u0 * 256 + tid;
                float x = (u0 == 0) ? a0 : (u0 == 1) ? a1 : a2;
                unsigned short hi = f2bf(x);
                unsigned short lo = f2bf(x - bf2f(hi));
                dst[u] = hi; dst[DD + u] = lo;
            }
        }
    } else {
        const int r0 = (bid - 408) * 4;
        #pragma unroll
        for (int rr = 0; rr < 4; ++rr) {
            const int rw = r0 + rr;
            const int jj = rw / 768;
            const int d  = rw - jj * 768;
            const float* src = W + (size_t)jj * WSLICE + (size_t)d * DD;
            unsigned short* dst = B2 + (size_t)rw * K2S;
            #pragma unroll
            for (int u0 = 0; u0 < 3; ++u0) {
                const int u = u0 * 256 + tid;
                float x = src[u];
                unsigned short hi = f2bf(x);
                unsigned short lo = f2bf(x - bf2f(hi));
                dst[u] = hi; dst[DD + u] = lo;
            }
        }
    }
}

// ---------------- kernel 2: MFMA GEMM, BM=128 x BN=64, 2-phase dbuf -----------
__global__ __launch_bounds__(256) void k_gemm_mfma(const unsigned short* __restrict__ A2,
                                                   const unsigned short* __restrict__ B2,
                                                   float* __restrict__ H)
{
    __shared__ __align__(16) unsigned short lds[2][12288];  // A:[0,8192) B:[8192,12288)
    const int tid = threadIdx.x;
    const int wv  = tid >> 6;
    const int ln  = tid & 63;
    const int c0  = blockIdx.x * 64;
    const int m0  = blockIdx.y * 128;
    const int wm  = (wv >> 1) * 64;
    const int wn  = (wv & 1) * 32;
    const unsigned short* Ap = A2 + (size_t)m0 * K2S;
    const unsigned short* Bp = B2 + (size_t)c0 * K2S;

    float4v acc[4][2];
    #pragma unroll
    for (int a = 0; a < 4; ++a)
        #pragma unroll
        for (int b = 0; b < 2; ++b)
            acc[a][b] = (float4v){0.f, 0.f, 0.f, 0.f};

#define STAGE(buf, ka, kb) {                                                      \
    _Pragma("unroll")                                                             \
    for (int qq = 0; qq < 4; ++qq) {                                              \
        const int idx = (qq << 8) + tid;                                          \
        const int row = idx >> 3;                                                 \
        const int ce  = ((idx & 7) ^ (row & 7)) << 3;                             \
        __builtin_amdgcn_global_load_lds(                                         \
            (const __attribute__((address_space(1))) void*)(Ap + (size_t)row * K2S + (ka) + ce), \
            (__attribute__((address_space(3))) void*)(&lds[buf][idx * 8]), 16, 0, 0);            \
    }                                                                             \
    _Pragma("unroll")                                                             \
    for (int qq = 0; qq < 2; ++qq) {                                              \
        const int idx = (qq << 8) + tid;                                          \
        const int row = idx >> 3;                                                 \
        const int ce  = ((idx & 7) ^ (row & 7)) << 3;                             \
        __builtin_amdgcn_global_load_lds(                                         \
            (const __attribute__((address_space(1))) void*)(Bp + (size_t)row * K2S + (kb) + ce), \
            (__attribute__((address_space(3))) void*)(&lds[buf][8192 + idx * 8]), 16, 0, 0);     \
    } }

#define COMPUTE(buf) { _Pragma("unroll")                                          \
    for (int s = 0; s < 2; ++s) {                                                 \
        short8v af[4], bf[2];                                                     \
        _Pragma("unroll")                                                         \
        for (int mi = 0; mi < 4; ++mi) {                                          \
            const int row = wm + mi * 16 + (ln & 15);                             \
            const int off = row * 64 + ((s * 32 + ((ln >> 4) * 8)) ^ ((row & 7) << 3)); \
            af[mi] = *reinterpret_cast<const short8v*>(&lds[buf][off]);           \
        }                                                                         \
        _Pragma("unroll")                                                         \
        for (int ni = 0; ni < 2; ++ni) {                                          \
            const int row = wn + ni * 16 + (ln & 15);                             \
            const int off = row * 64 + ((s * 32 + ((ln >> 4) * 8)) ^ ((row & 7) << 3)); \
            bf[ni] = *reinterpret_cast<const short8v*>(&lds[buf][8192 + off]);    \
        }                                                                         \
        _Pragma("unroll")                                                         \
        for (int mi = 0; mi < 4; ++mi)                                            \
            _Pragma("unroll")                                                     \
            for (int ni = 0; ni < 2; ++ni)                                        \
                acc[mi][ni] = __builtin_amdgcn_mfma_f32_16x16x32_bf16(af[mi], bf[ni], acc[mi][ni], 0, 0, 0); \
    } }

    STAGE(0, 0, 0);
    __syncthreads();
    int cur = 0;
    for (int k0 = 64; k0 < K2; k0 += 64) {
        const int ka = (k0 < 1536) ? k0 : k0 - 1536;   // hi | lo | hi
        const int kb = (k0 < 768)  ? k0 : k0 - 768;    // hi | hi | lo
        STAGE(cur ^ 1, ka, kb);
        COMPUTE(cur);
        __syncthreads();
        cur ^= 1;
    }
    COMPUTE(cur);
#undef STAGE
#undef COMPUTE

    #pragma unroll
    for (int mi = 0; mi < 4; ++mi) {
        #pragma unroll
        for (int r = 0; r < 4; ++r) {
            const int gr = m0 + wm + mi * 16 + (ln >> 4) * 4 + r;
            if (gr < NROWS) {
                #pragma unroll
                for (int ni = 0; ni < 2; ++ni)
                    H[(size_t)gr * JD + c0 + wn + ni * 16 + (ln & 15)] = acc[mi][ni][r];
            }
        }
    }
}

// ---------------- kernel 3: merged prep / gram / dots -------------------------
__global__ __launch_bounds__(256) void k_mid(const float* __restrict__ H,
                                             const float* __restrict__ b,
                                             float* __restrict__ hm,
                                             float* __restrict__ muM,
                                             float* __restrict__ mc2M,
                                             float* __restrict__ G,
                                             float* __restrict__ dmq,
                                             float* __restrict__ Sq0v,
                                             float* __restrict__ Sq20v)
{
    const int bid = blockIdx.x;
    const int tid = threadIdx.x;
    const int lane = tid & 63, wave = tid >> 6;
    __shared__ __align__(16) float Ms[8][768];
    __shared__ float scr[8][4];
    __shared__ float smu;

    if (bid < 64) {
        // ---------------- prep ----------------
        const int ji = bid;
        const int j = ji >> 3, i = ji & 7;
        float vals[3];
        float s = 0.f;
        #pragma unroll
        for (int u = 0; u < 3; ++u) {
            const int d = u * 256 + tid;
            float x = H[(size_t)(NQ + i) * JD + j * DD + d] + b[(size_t)ji * DD + d];
            hm[(size_t)ji * DD + d] = x;
            vals[u] = x;
            s += x;
        }
        #pragma unroll
        for (int off = 32; off; off >>= 1) s += __shfl_down(s, off);
        if (lane == 0) scr[0][wave] = s;
        __syncthreads();
        if (tid == 0) smu = (scr[0][0] + scr[0][1] + scr[0][2] + scr[0][3]) * (1.f / 768.f);
        __syncthreads();
        const float mu = smu;
        float s2 = 0.f;
        #pragma unroll
        for (int u = 0; u < 3; ++u) { float c = vals[u] - mu; s2 += c * c; }
        __syncthreads();
        #pragma unroll
        for (int off = 32; off; off >>= 1) s2 += __shfl_down(s2, off);
        if (lane == 0) scr[0][wave] = s2;
        __syncthreads();
        if (tid == 0) { muM[ji] = mu; mc2M[ji] = scr[0][0] + scr[0][1] + scr[0][2] + scr[0][3]; }
    } else if (bid < 128) {
        // ---------------- gram ----------------
        const int ji = bid - 64;
        const int j = ji >> 3, i = ji & 7;
        const float* Hj = H + j * DD;
        const float* bj = b + (size_t)(j * 8) * DD;
        const float a0 = Hj[(size_t)(NQ + i) * JD + tid]       + bj[(size_t)i * DD + tid];
        const float a1 = Hj[(size_t)(NQ + i) * JD + 256 + tid] + bj[(size_t)i * DD + 256 + tid];
        const float a2 = Hj[(size_t)(NQ + i) * JD + 512 + tid] + bj[(size_t)i * DD + 512 + tid];
#define GDOT(k) { const float* Hp = Hj + (size_t)(NQ + k) * JD + tid;            \
        const float* bp = bj + (size_t)k * DD + tid;                             \
        float acc = a0*(Hp[0]+bp[0]) + a1*(Hp[256]+bp[256]) + a2*(Hp[512]+bp[512]); \
        acc += __shfl_down(acc, 32); acc += __shfl_down(acc, 16);                \
        acc += __shfl_down(acc, 8);  acc += __shfl_down(acc, 4);                 \
        acc += __shfl_down(acc, 2);  acc += __shfl_down(acc, 1);                 \
        if (lane == 0) scr[k][wave] = acc; }
        FOR8(GDOT)
#undef GDOT
        __syncthreads();
        if (tid < 8) G[ji*8 + tid] = scr[tid][0] + scr[tid][1] + scr[tid][2] + scr[tid][3];
    } else {
        // ---------------- dots ----------------
        const int t = bid - 128;
        const int j = t & 7;
        const int tile = t >> 3;            // 0..15, 25 n each
        #pragma unroll
        for (int r = 0; r < 8; ++r)
            for (int c = tid; c < DD; c += 256)
                Ms[r][c] = H[(size_t)(NQ + r) * JD + j * DD + c] + b[(size_t)(j * 8 + r) * DD + c];
        __syncthreads();

        for (int nn = wave; nn < 25; nn += 4) {
            const int n = tile * 25 + nn;
            const float* qp = H + (size_t)n * JD + j * DD;
            float s = 0.f, s2 = 0.f;
#define DCL(k) float d##k = 0.f;
            FOR8(DCL)
#undef DCL
            #pragma unroll 2
            for (int c = 0; c < 12; ++c) {
                const int d = lane + 64 * c;
                const float qv = qp[d];
                s += qv; s2 += qv * qv;
#define MAC(k) d##k += qv * Ms[k][d];
                FOR8(MAC)
#undef MAC
            }
#define XR(v) { v += __shfl_xor(v, 32); v += __shfl_xor(v, 16); v += __shfl_xor(v, 8); \
                v += __shfl_xor(v, 4);  v += __shfl_xor(v, 2);  v += __shfl_xor(v, 1); }
#define XRD(k) XR(d##k)
            FOR8(XRD)
#undef XRD
            XR(s) XR(s2)
#undef XR
            if (lane == 0) {
#define ST(k) dmq[(size_t)n*64 + j*8 + k] = d##k;
                FOR8(ST)
#undef ST
                Sq0v[n*8 + j] = s;
                Sq20v[n*8 + j] = s2;
            }
        }
    }
}

// ---------------- kernel 4: fused routing, 256 threads x 3 d-values -----------
// 256-thread blocks get a full VGPR budget (vs the 84-reg cap observed on
// 768-thread blocks) -> per-thread state (t0/tq1/vh = float[8][3], statically
// indexed) lives in registers, no scratch.
__global__ __launch_bounds__(256) void k_route2(const float* __restrict__ H,
                                                const float* __restrict__ hm,
                                                const float* __restrict__ muM,
                                                const float* __restrict__ mc2M,
                                                const float* __restrict__ G,
                                                const float* __restrict__ dmq,
                                                const float* __restrict__ Sq0v,
                                                const float* __restrict__ Sq20v,
                                                float* __restrict__ out)
{
    const int n = blockIdx.x;
    const int tid = threadIdx.x;                  // d base; thread owns d = u*256+tid
    const int lane = tid & 63, wave = tid >> 6;   // 4 waves
    __shared__ __align__(16) float sVv[8][768];
    __shared__ float scr[24][4];
    __shared__ float rstat[24];
    __shared__ float sDot[64];
    __shared__ float sP[64], sC1[64], sC2[64], sB1[64];

#define WRED(val, idx) { float _v = (val);                           \
    _v += __shfl_down(_v, 32); _v += __shfl_down(_v, 16);            \
    _v += __shfl_down(_v, 8);  _v += __shfl_down(_v, 4);             \
    _v += __shfl_down(_v, 2);  _v += __shfl_down(_v, 1);             \
    if (lane == 0) scr[(idx)][wave] = _v; }

#define FIN(nv) { if (tid < (nv))                                    \
    rstat[tid] = scr[tid][0] + scr[tid][1] + scr[tid][2] + scr[tid][3]; }

#define DOTLOOP() for (int t = wave; t < 64; t += 4) {               \
        const int _j = t >> 3;                                       \
        const float* Mrow = hm + (size_t)t * DD;                     \
        float acc = 0.f;                                             \
        _Pragma("unroll")                                            \
        for (int c = 0; c < 3; ++c) {                                \
            const int dd = c * 256 + lane * 4;                       \
            const float4 mv = *reinterpret_cast<const float4*>(Mrow + dd);       \
            const float4 vv = *reinterpret_cast<const float4*>(&sVv[_j][dd]);    \
            acc += mv.x*vv.x + mv.y*vv.y + mv.z*vv.z + mv.w*vv.w;    \
        }                                                            \
        acc += __shfl_down(acc, 32); acc += __shfl_down(acc, 16);    \
        acc += __shfl_down(acc, 8);  acc += __shfl_down(acc, 4);     \
        acc += __shfl_down(acc, 2);  acc += __shfl_down(acc, 1);     \
        if (lane == 0) sDot[t] = acc;                                \
    }

#define XR3(v) { v += __shfl_xor(v, 1); v += __shfl_xor(v, 2); v += __shfl_xor(v, 4); }

    // ---- stage 0 (wave 0): coefficient-space routing iteration 1 ----
    float w0 = 0.f, s1 = 0.f, dotM1 = 0.f, Sq1 = 0.f, Sq21 = 0.f, mu = 0.f, mc2 = 0.f;
    if (tid < 64) {
        const int j = lane >> 3;
        mu  = muM[lane];
        mc2 = mc2M[lane];
        const float smR = 768.f * mu;              // sum of M row
        const float dq  = dmq[(size_t)n * 64 + lane];
        const float Sq  = Sq0v[n * 8 + j];
        const float Sq2v = Sq20v[n * 8 + j];
        {
            float num  = dq - mu * Sq;
            float varq = fmaxf(Sq2v - Sq * Sq * (1.f / 768.f), 0.f);
            float den  = sqrtf(mc2 * varq) + EPSF;
            w0 = tanhf(num / den) + 0.125f;        // w0 = 1/8 + p0
        }
        const float* Gr = G + lane * 8;
        const int base = lane & ~7;
        float gw = 0.f;
        #pragma unroll
        for (int ii = 0; ii < 8; ++ii) gw += Gr[ii] * __shfl(w0, base + ii);
        float n2h1 = w0 * gw;  XR3(n2h1);          // |hv1|^2
        float dqh1 = w0 * dq;  XR3(dqh1);          // dot(q', hv1)
        float Sh1  = w0 * smR; XR3(Sh1);           // sum(hv1)
        s1 = n2h1 / ((1.f + n2h1) * sqrtf(n2h1 + EPSF));
        float c1 = s1 * gw;
        sC1[lane] = c1;
        sB1[lane] = 0.5f * s1 * w0;
        dotM1 = 0.5f * (dq + c1);
        Sq1   = 0.5f * (Sq + s1 * Sh1);
        Sq21  = 0.25f * (Sq2v + 2.f * s1 * dqh1 + s1 * s1 * n2h1);   // |tq1|^2
        float varq1 = fmaxf(Sq21 - Sq1 * Sq1 * (1.f / 768.f), 0.f);
        sP[lane] = tanhf((dotM1 - mu * Sq1) / (sqrtf(mc2 * varq1) + EPSF));  // p1
    }
    __syncthreads();

    // ---- pass 1 (d-space): hv2 + tq1 reconstruction ----
    const float* Hn = H + (size_t)n * JD + tid;
    const float* hmp = hm + tid;
    float t0[8][3], tq1[8][3], vh[8][3];
    #pragma unroll
    for (int k = 0; k < 8; ++k)
        #pragma unroll
        for (int u = 0; u < 3; ++u) {
            t0[k][u] = Hn[k * DD + u * 256];
            tq1[k][u] = 0.5f * t0[k][u];
            vh[k][u] = 0.f;
        }
    #pragma unroll 1
    for (int i = 0; i < 8; ++i) {
        float c1v[8], pv[8], b1v[8];
        #pragma unroll
        for (int k = 0; k < 8; ++k) { c1v[k] = sC1[k*8+i]; pv[k] = sP[k*8+i]; b1v[k] = sB1[k*8+i]; }
        #pragma unroll
        for (int u = 0; u < 3; ++u) {
            float x[8];
            #pragma unroll
            for (int k = 0; k < 8; ++k) x[k] = t0[k][u] * c1v[k];
            float mx = fmaxf(fmaxf(fmaxf(x[0], x[1]), fmaxf(x[2], x[3])),
                             fmaxf(fmaxf(x[4], x[5]), fmaxf(x[6], x[7])));
            float es = 0.f;
            #pragma unroll
            for (int k = 0; k < 8; ++k) { x[k] = __expf(x[k] - mx); es += x[k]; }
            float inv = 1.f / es;
            #pragma unroll
            for (int k = 0; k < 8; ++k) {
                const float mval = hmp[(size_t)(k * 8 + i) * DD + u * 256];
                vh[k][u]  += (x[k] * inv + pv[k]) * mval;
                tq1[k][u] += b1v[k] * mval;
            }
        }
    }
    #pragma unroll
    for (int k = 0; k < 8; ++k) {
        float p2 = 0.f, p1 = 0.f, p0 = 0.f;
        #pragma unroll
        for (int u = 0; u < 3; ++u) {
            sVv[k][u * 256 + tid] = vh[k][u];
            p2 += vh[k][u] * vh[k][u];
            p1 += vh[k][u];
            p0 += t0[k][u] * vh[k][u];
        }
        WRED(p2, k); WRED(p1, 8 + k); WRED(p0, 16 + k);
    }
    __syncthreads();
    // ---- pass 2: u[ji] = M_ji . hv2_j ----
    DOTLOOP();
    FIN(24);
    __syncthreads();

    // ---- stage 2 (wave 0): p2, c2 ----
    if (tid < 64) {
        const int j = lane >> 3;
        const float n2h2 = rstat[j];               // |hv2|^2
        const float Sh2  = rstat[8 + j];           // sum(hv2)
        const float dqh2 = rstat[16 + j];          // dot(q', hv2)
        const float u = sDot[lane];                // dot(M_ji, hv2_j)
        float s2 = n2h2 / ((1.f + n2h2) * sqrtf(n2h2 + EPSF));
        float c2 = s2 * u;
        sC2[lane] = c2;
        float dotM2 = 0.5f * (dotM1 + c2);
        float w0u = w0 * u; XR3(w0u);              // dot(hv1, hv2)
        float dt1h2 = 0.5f * (dqh2 + s1 * w0u);    // dot(tq1, hv2)
        float Sq2_ = 0.5f * (Sq1 + s2 * Sh2);
        float Sq22 = 0.25f * Sq21 + 0.5f * s2 * dt1h2 + 0.25f * s2 * s2 * n2h2;  // |tq2|^2
        float varq2 = fmaxf(Sq22 - Sq2_ * Sq2_ * (1.f / 768.f), 0.f);
        sP[lane] = tanhf((dotM2 - mu * Sq2_) / (sqrtf(mc2 * varq2) + EPSF));     // p2
    }
    __syncthreads();

    // ---- pass 3 (d-space): final softmax + hv3 + squash + write ----
    #pragma unroll
    for (int k = 0; k < 8; ++k)
        #pragma unroll
        for (int u = 0; u < 3; ++u) vh[k][u] = 0.f;
    #pragma unroll 1
    for (int i = 0; i < 8; ++i) {
        float c1v[8], c2v[8], pv[8];
        #pragma unroll
        for (int k = 0; k < 8; ++k) { c1v[k] = sC1[k*8+i]; c2v[k] = sC2[k*8+i]; pv[k] = sP[k*8+i]; }
        #pragma unroll
        for (int u = 0; u < 3; ++u) {
            float x[8];
            #pragma unroll
            for (int k = 0; k < 8; ++k) x[k] = t0[k][u] * c1v[k] + tq1[k][u] * c2v[k];
            float mx = fmaxf(fmaxf(fmaxf(x[0], x[1]), fmaxf(x[2], x[3])),
                             fmaxf(fmaxf(x[4], x[5]), fmaxf(x[6], x[7])));
            float es = 0.f;
            #pragma unroll
            for (int k = 0; k < 8; ++k) { x[k] = __expf(x[k] - mx); es += x[k]; }
            float inv = 1.f / es;
            #pragma unroll
            for (int k = 0; k < 8; ++k)
                vh[k][u] += (x[k] * inv + pv[k]) * hmp[(size_t)(k * 8 + i) * DD + u * 256];
        }
    }
    #pragma unroll
    for (int k = 0; k < 8; ++k) {
        float p2 = vh[k][0]*vh[k][0] + vh[k][1]*vh[k][1] + vh[k][2]*vh[k][2];
        WRED(p2, k);
    }
    __syncthreads();
    FIN(8);
    __syncthreads();
    float* On = out + (size_t)n * JD + tid;
    #pragma unroll
    for (int k = 0; k < 8; ++k) {
        float n2 = rstat[k];
        float sc = n2 / ((1.f + n2) * sqrtf(n2 + EPSF));
        #pragma unroll
        for (int u = 0; u < 3; ++u)
            On[k * DD + u * 256] = vh[k][u] * sc;
    }
#undef WRED
#undef FIN
#undef DOTLOOP
#undef XR3
}

extern "C" void kernel_launch(void* const* d_in, const int* in_sizes, int n_in,
                              void* d_out, int out_size, void* d_ws, size_t ws_size,
                              hipStream_t stream) {
    const float* m  = (const float*)d_in[0];   // [8,768]
    const float* q  = (const float*)d_in[1];   // [400,768]
    const float* W  = (const float*)d_in[2];   // [1,8,8,768,768]
    const float* b  = (const float*)d_in[3];   // [1,8,8,768]
    const float* Wn = (const float*)d_in[4];   // [768,768]
    float* out = (float*)d_out;
    float* ws  = (float*)d_ws;

    float* H     = ws + OFF_H;
    float* hm    = ws + OFF_HM;
    float* muM   = ws + OFF_MU;
    float* mc2M  = ws + OFF_MC2;
    float* G     = ws + OFF_G;
    float* dmq   = ws + OFF_DMQ;
    float* Sq0v  = ws + OFF_SQ0;
    float* Sq20v = ws + OFF_SQ20;
    unsigned short* A2 = (unsigned short*)(ws + OFF_A2);
    unsigned short* B2 = (unsigned short*)(ws + OFF_B2);

    k_cvt<<<dim3(1944), 256, 0, stream>>>(q, m, Wn, W, A2, B2);
    k_gemm_mfma<<<dim3(96, 4), 256, 0, stream>>>(A2, B2, H);
    k_mid<<<dim3(256), 256, 0, stream>>>(H, b, hm, muM, mc2M, G, dmq, Sq0v, Sq20v);
    k_route2<<<dim3(400), 256, 0, stream>>>(H, hm, muM, mc2M, G, dmq, Sq0v, Sq20v, out);
}

// Round 12
// 135.671 us; speedup vs baseline: 1.9447x; 1.0508x over previous
//
#include <hip/hip_runtime.h>
#include <math.h>

#define DD    768
#define NQ    400
#define NROWS 408          // 400 q rows + 8 m_proj rows
#define JD    6144         // J*D = 8*768
#define WSLICE 4718592     // I*D*E = 8*768*768 (stride between j slices of W)
#define EPSF  1e-8f
#define K2    2304         // effective split-bf16 K (3 segments of 768)
#define K2S   1536         // stored K (hi|lo, dedup'd)

// ---------------- workspace layout (floats) ----------------
#define OFF_H     0                       // [408][6144]
#define OFF_HM    (OFF_H + 408*6144)      // [64][768]  (j*8+i major)
#define OFF_MU    (OFF_HM + 64*768)       // [64]
#define OFF_MC2   (OFF_MU + 64)           // [64]
#define OFF_G     (OFF_MC2 + 64)          // [64][8]  Gram
#define OFF_DMQ   (OFF_G + 512)           // [400][64] dot(M_ji, q'_nj)
#define OFF_SQ0   (OFF_DMQ + 400*64)      // [400][8]  sum(q'_nj)
#define OFF_SQ20  (OFF_SQ0 + 400*8)       // [400][8]  sumsq(q'_nj)
#define OFF_A2    (OFF_SQ20 + 400*8)      // [512][1536] bf16 (as u16)
#define OFF_B2    (OFF_A2 + 512*K2S/2)    // [6144][1536] bf16 (as u16)

#define FOR8(M) M(0) M(1) M(2) M(3) M(4) M(5) M(6) M(7)

typedef __attribute__((ext_vector_type(8))) short short8v;
typedef __attribute__((ext_vector_type(4))) float float4v;

__device__ inline unsigned short f2bf(float x) {
    unsigned u = __float_as_uint(x);
    u += 0x7FFF + ((u >> 16) & 1);
    return (unsigned short)(u >> 16);
}
__device__ inline float bf2f(unsigned short h) {
    return __uint_as_float(((unsigned)h) << 16);
}

// ---------------- kernel 1: pack A'=[hi|lo] and B'=[hi|lo] --------------------
__global__ __launch_bounds__(256) void k_cvt(const float* __restrict__ q,
                                             const float* __restrict__ m,
                                             const float* __restrict__ Wn,
                                             const float* __restrict__ W,
                                             unsigned short* __restrict__ A2,
                                             unsigned short* __restrict__ B2)
{
    const int bid = blockIdx.x;
    const int tid = threadIdx.x;
    if (bid < 408) {
        const int r = bid;
        unsigned short* dst = A2 + (size_t)r * K2S;
        if (r < NQ) {
            const float* src = q + (size_t)r * DD;
            #pragma unroll
            for (int u0 = 0; u0 < 3; ++u0) {
                const int u = u0 * 256 + tid;
                float x = src[u];
                unsigned short hi = f2bf(x);
                unsigned short lo = f2bf(x - bf2f(hi));
                dst[u] = hi; dst[DD + u] = lo;
            }
        } else {
            const int i = r - NQ;
            float a0 = 0.f, a1 = 0.f, a2 = 0.f;
            #pragma unroll 8
            for (int e = 0; e < DD; ++e) {
                const float mv = m[i*DD + e];
                const float* wr = Wn + (size_t)e * DD;
                a0 += mv * wr[tid];
                a1 += mv * wr[tid + 256];
                a2 += mv * wr[tid + 512];
            }
            #pragma unroll
            for (int u0 = 0; u0 < 3; ++u0) {
                const int u = u0 * 256 + tid;
                float x = (u0 == 0) ? a0 : (u0 == 1) ? a1 : a2;
                unsigned short hi = f2bf(x);
                unsigned short lo = f2bf(x - bf2f(hi));
                dst[u] = hi; dst[DD + u] = lo;
            }
        }
    } else {
        const int r0 = (bid - 408) * 4;
        #pragma unroll
        for (int rr = 0; rr < 4; ++rr) {
            const int rw = r0 + rr;
            const int jj = rw / 768;
            const int d  = rw - jj * 768;
            const float* src = W + (size_t)jj * WSLICE + (size_t)d * DD;
            unsigned short* dst = B2 + (size_t)rw * K2S;
            #pragma unroll
            for (int u0 = 0; u0 < 3; ++u0) {
                const int u = u0 * 256 + tid;
                float x = src[u];
                unsigned short hi = f2bf(x);
                unsigned short lo = f2bf(x - bf2f(hi));
                dst[u] = hi; dst[DD + u] = lo;
            }
        }
    }
}

// ---------------- kernel 2: MFMA GEMM, BM=128 x BN=64, 2-phase dbuf -----------
__global__ __launch_bounds__(256) void k_gemm_mfma(const unsigned short* __restrict__ A2,
                                                   const unsigned short* __restrict__ B2,
                                                   float* __restrict__ H)
{
    __shared__ __align__(16) unsigned short lds[2][12288];  // A:[0,8192) B:[8192,12288)
    const int tid = threadIdx.x;
    const int wv  = tid >> 6;
    const int ln  = tid & 63;
    const int c0  = blockIdx.x * 64;
    const int m0  = blockIdx.y * 128;
    const int wm  = (wv >> 1) * 64;
    const int wn  = (wv & 1) * 32;
    const unsigned short* Ap = A2 + (size_t)m0 * K2S;
    const unsigned short* Bp = B2 + (size_t)c0 * K2S;

    float4v acc[4][2];
    #pragma unroll
    for (int a = 0; a < 4; ++a)
        #pragma unroll
        for (int b = 0; b < 2; ++b)
            acc[a][b] = (float4v){0.f, 0.f, 0.f, 0.f};

#define STAGE(buf, ka, kb) {                                                      \
    _Pragma("unroll")                                                             \
    for (int qq = 0; qq < 4; ++qq) {                                              \
        const int idx = (qq << 8) + tid;                                          \
        const int row = idx >> 3;                                                 \
        const int ce  = ((idx & 7) ^ (row & 7)) << 3;                             \
        __builtin_amdgcn_global_load_lds(                                         \
            (const __attribute__((address_space(1))) void*)(Ap + (size_t)row * K2S + (ka) + ce), \
            (__attribute__((address_space(3))) void*)(&lds[buf][idx * 8]), 16, 0, 0);            \
    }                                                                             \
    _Pragma("unroll")                                                             \
    for (int qq = 0; qq < 2; ++qq) {                                              \
        const int idx = (qq << 8) + tid;                                          \
        const int row = idx >> 3;                                                 \
        const int ce  = ((idx & 7) ^ (row & 7)) << 3;                             \
        __builtin_amdgcn_global_load_lds(                                         \
            (const __attribute__((address_space(1))) void*)(Bp + (size_t)row * K2S + (kb) + ce), \
            (__attribute__((address_space(3))) void*)(&lds[buf][8192 + idx * 8]), 16, 0, 0);     \
    } }

#define COMPUTE(buf) { _Pragma("unroll")                                          \
    for (int s = 0; s < 2; ++s) {                                                 \
        short8v af[4], bf[2];                                                     \
        _Pragma("unroll")                                                         \
        for (int mi = 0; mi < 4; ++mi) {                                          \
            const int row = wm + mi * 16 + (ln & 15);                             \
            const int off = row * 64 + ((s * 32 + ((ln >> 4) * 8)) ^ ((row & 7) << 3)); \
            af[mi] = *reinterpret_cast<const short8v*>(&lds[buf][off]);           \
        }                                                                         \
        _Pragma("unroll")                                                         \
        for (int ni = 0; ni < 2; ++ni) {                                          \
            const int row = wn + ni * 16 + (ln & 15);                             \
            const int off = row * 64 + ((s * 32 + ((ln >> 4) * 8)) ^ ((row & 7) << 3)); \
            bf[ni] = *reinterpret_cast<const short8v*>(&lds[buf][8192 + off]);    \
        }                                                                         \
        _Pragma("unroll")                                                         \
        for (int mi = 0; mi < 4; ++mi)                                            \
            _Pragma("unroll")                                                     \
            for (int ni = 0; ni < 2; ++ni)                                        \
                acc[mi][ni] = __builtin_amdgcn_mfma_f32_16x16x32_bf16(af[mi], bf[ni], acc[mi][ni], 0, 0, 0); \
    } }

    STAGE(0, 0, 0);
    __syncthreads();
    int cur = 0;
    for (int k0 = 64; k0 < K2; k0 += 64) {
        const int ka = (k0 < 1536) ? k0 : k0 - 1536;   // hi | lo | hi
        const int kb = (k0 < 768)  ? k0 : k0 - 768;    // hi | hi | lo
        STAGE(cur ^ 1, ka, kb);
        COMPUTE(cur);
        __syncthreads();
        cur ^= 1;
    }
    COMPUTE(cur);
#undef STAGE
#undef COMPUTE

    #pragma unroll
    for (int mi = 0; mi < 4; ++mi) {
        #pragma unroll
        for (int r = 0; r < 4; ++r) {
            const int gr = m0 + wm + mi * 16 + (ln >> 4) * 4 + r;
            if (gr < NROWS) {
                #pragma unroll
                for (int ni = 0; ni < 2; ++ni)
                    H[(size_t)gr * JD + c0 + wn + ni * 16 + (ln & 15)] = acc[mi][ni][r];
            }
        }
    }
}

// ---------------- kernel 3: merged prep / gram / dots -------------------------
__global__ __launch_bounds__(256) void k_mid(const float* __restrict__ H,
                                             const float* __restrict__ b,
                                             float* __restrict__ hm,
                                             float* __restrict__ muM,
                                             float* __restrict__ mc2M,
                                             float* __restrict__ G,
                                             float* __restrict__ dmq,
                                             float* __restrict__ Sq0v,
                                             float* __restrict__ Sq20v)
{
    const int bid = blockIdx.x;
    const int tid = threadIdx.x;
    const int lane = tid & 63, wave = tid >> 6;
    __shared__ __align__(16) float Ms[8][768];
    __shared__ float scr[8][4];
    __shared__ float smu;

    if (bid < 64) {
        // ---------------- prep ----------------
        const int ji = bid;
        const int j = ji >> 3, i = ji & 7;
        float vals[3];
        float s = 0.f;
        #pragma unroll
        for (int u = 0; u < 3; ++u) {
            const int d = u * 256 + tid;
            float x = H[(size_t)(NQ + i) * JD + j * DD + d] + b[(size_t)ji * DD + d];
            hm[(size_t)ji * DD + d] = x;
            vals[u] = x;
            s += x;
        }
        #pragma unroll
        for (int off = 32; off; off >>= 1) s += __shfl_down(s, off);
        if (lane == 0) scr[0][wave] = s;
        __syncthreads();
        if (tid == 0) smu = (scr[0][0] + scr[0][1] + scr[0][2] + scr[0][3]) * (1.f / 768.f);
        __syncthreads();
        const float mu = smu;
        float s2 = 0.f;
        #pragma unroll
        for (int u = 0; u < 3; ++u) { float c = vals[u] - mu; s2 += c * c; }
        __syncthreads();
        #pragma unroll
        for (int off = 32; off; off >>= 1) s2 += __shfl_down(s2, off);
        if (lane == 0) scr[0][wave] = s2;
        __syncthreads();
        if (tid == 0) { muM[ji] = mu; mc2M[ji] = scr[0][0] + scr[0][1] + scr[0][2] + scr[0][3]; }
    } else if (bid < 128) {
        // ---------------- gram ----------------
        const int ji = bid - 64;
        const int j = ji >> 3, i = ji & 7;
        const float* Hj = H + j * DD;
        const float* bj = b + (size_t)(j * 8) * DD;
        const float a0 = Hj[(size_t)(NQ + i) * JD + tid]       + bj[(size_t)i * DD + tid];
        const float a1 = Hj[(size_t)(NQ + i) * JD + 256 + tid] + bj[(size_t)i * DD + 256 + tid];
        const float a2 = Hj[(size_t)(NQ + i) * JD + 512 + tid] + bj[(size_t)i * DD + 512 + tid];
#define GDOT(k) { const float* Hp = Hj + (size_t)(NQ + k) * JD + tid;            \
        const float* bp = bj + (size_t)k * DD + tid;                             \
        float acc = a0*(Hp[0]+bp[0]) + a1*(Hp[256]+bp[256]) + a2*(Hp[512]+bp[512]); \
        acc += __shfl_down(acc, 32); acc += __shfl_down(acc, 16);                \
        acc += __shfl_down(acc, 8);  acc += __shfl_down(acc, 4);                 \
        acc += __shfl_down(acc, 2);  acc += __shfl_down(acc, 1);                 \
        if (lane == 0) scr[k][wave] = acc; }
        FOR8(GDOT)
#undef GDOT
        __syncthreads();
        if (tid < 8) G[ji*8 + tid] = scr[tid][0] + scr[tid][1] + scr[tid][2] + scr[tid][3];
    } else {
        // ---------------- dots ----------------
        const int t = bid - 128;
        const int j = t & 7;
        const int tile = t >> 3;            // 0..15, 25 n each
        #pragma unroll
        for (int r = 0; r < 8; ++r)
            for (int c = tid; c < DD; c += 256)
                Ms[r][c] = H[(size_t)(NQ + r) * JD + j * DD + c] + b[(size_t)(j * 8 + r) * DD + c];
        __syncthreads();

        for (int nn = wave; nn < 25; nn += 4) {
            const int n = tile * 25 + nn;
            const float* qp = H + (size_t)n * JD + j * DD;
            float s = 0.f, s2 = 0.f;
#define DCL(k) float d##k = 0.f;
            FOR8(DCL)
#undef DCL
            #pragma unroll 2
            for (int c = 0; c < 12; ++c) {
                const int d = lane + 64 * c;
                const float qv = qp[d];
                s += qv; s2 += qv * qv;
#define MAC(k) d##k += qv * Ms[k][d];
                FOR8(MAC)
#undef MAC
            }
#define XR(v) { v += __shfl_xor(v, 32); v += __shfl_xor(v, 16); v += __shfl_xor(v, 8); \
                v += __shfl_xor(v, 4);  v += __shfl_xor(v, 2);  v += __shfl_xor(v, 1); }
#define XRD(k) XR(d##k)
            FOR8(XRD)
#undef XRD
            XR(s) XR(s2)
#undef XR
            if (lane == 0) {
#define ST(k) dmq[(size_t)n*64 + j*8 + k] = d##k;
                FOR8(ST)
#undef ST
                Sq0v[n*8 + j] = s;
                Sq20v[n*8 + j] = s2;
            }
        }
    }
}

// ---------------- kernel 4: fused routing, 256 thr x 3 d, BATCHED LOADS -------
// G7: all hm loads for an i-iteration are hoisted into a statically-indexed
// mv[8][3] BEFORE any use -> one waitcnt per 24 loads instead of per-load
// serialization (R11 post-mortem: route2 was ~60us, 6x its bottom-up cost,
// signature of serial L2 loads).
__global__ __launch_bounds__(256) void k_route2(const float* __restrict__ H,
                                                const float* __restrict__ hm,
                                                const float* __restrict__ muM,
                                                const float* __restrict__ mc2M,
                                                const float* __restrict__ G,
                                                const float* __restrict__ dmq,
                                                const float* __restrict__ Sq0v,
                                                const float* __restrict__ Sq20v,
                                                float* __restrict__ out)
{
    const int n = blockIdx.x;
    const int tid = threadIdx.x;                  // d base; thread owns d = u*256+tid
    const int lane = tid & 63, wave = tid >> 6;   // 4 waves
    __shared__ __align__(16) float sVv[8][768];
    __shared__ float scr[24][4];
    __shared__ float rstat[24];
    __shared__ float sDot[64];
    __shared__ float sP[64], sC1[64], sC2[64], sB1[64];

#define WRED(val, idx) { float _v = (val);                           \
    _v += __shfl_down(_v, 32); _v += __shfl_down(_v, 16);            \
    _v += __shfl_down(_v, 8);  _v += __shfl_down(_v, 4);             \
    _v += __shfl_down(_v, 2);  _v += __shfl_down(_v, 1);             \
    if (lane == 0) scr[(idx)][wave] = _v; }

#define FIN(nv) { if (tid < (nv))                                    \
    rstat[tid] = scr[tid][0] + scr[tid][1] + scr[tid][2] + scr[tid][3]; }

#define XR3(v) { v += __shfl_xor(v, 1); v += __shfl_xor(v, 2); v += __shfl_xor(v, 4); }

    // ---- stage 0 (wave 0): coefficient-space routing iteration 1 ----
    float w0 = 0.f, s1 = 0.f, dotM1 = 0.f, Sq1 = 0.f, Sq21 = 0.f, mu = 0.f, mc2 = 0.f;
    if (tid < 64) {
        const int j = lane >> 3;
        mu  = muM[lane];
        mc2 = mc2M[lane];
        const float smR = 768.f * mu;              // sum of M row
        const float dq  = dmq[(size_t)n * 64 + lane];
        const float Sq  = Sq0v[n * 8 + j];
        const float Sq2v = Sq20v[n * 8 + j];
        {
            float num  = dq - mu * Sq;
            float varq = fmaxf(Sq2v - Sq * Sq * (1.f / 768.f), 0.f);
            float den  = sqrtf(mc2 * varq) + EPSF;
            w0 = tanhf(num / den) + 0.125f;        // w0 = 1/8 + p0
        }
        const float* Gr = G + lane * 8;
        const int base = lane & ~7;
        float gw = 0.f;
        #pragma unroll
        for (int ii = 0; ii < 8; ++ii) gw += Gr[ii] * __shfl(w0, base + ii);
        float n2h1 = w0 * gw;  XR3(n2h1);          // |hv1|^2
        float dqh1 = w0 * dq;  XR3(dqh1);          // dot(q', hv1)
        float Sh1  = w0 * smR; XR3(Sh1);           // sum(hv1)
        s1 = n2h1 / ((1.f + n2h1) * sqrtf(n2h1 + EPSF));
        float c1 = s1 * gw;
        sC1[lane] = c1;
        sB1[lane] = 0.5f * s1 * w0;
        dotM1 = 0.5f * (dq + c1);
        Sq1   = 0.5f * (Sq + s1 * Sh1);
        Sq21  = 0.25f * (Sq2v + 2.f * s1 * dqh1 + s1 * s1 * n2h1);   // |tq1|^2
        float varq1 = fmaxf(Sq21 - Sq1 * Sq1 * (1.f / 768.f), 0.f);
        sP[lane] = tanhf((dotM1 - mu * Sq1) / (sqrtf(mc2 * varq1) + EPSF));  // p1
    }
    __syncthreads();

    // ---- pass 1 (d-space): hv2 + tq1 reconstruction, batched loads ----
    const float* Hn = H + (size_t)n * JD + tid;
    const float* hmp = hm + tid;
    float t0[8][3], tq1[8][3], vh[8][3];
    {
        float tv[8][3];
        #pragma unroll
        for (int k = 0; k < 8; ++k)
            #pragma unroll
            for (int u = 0; u < 3; ++u)
                tv[k][u] = Hn[k * DD + u * 256];
        #pragma unroll
        for (int k = 0; k < 8; ++k)
            #pragma unroll
            for (int u = 0; u < 3; ++u) {
                t0[k][u] = tv[k][u];
                tq1[k][u] = 0.5f * tv[k][u];
                vh[k][u] = 0.f;
            }
    }
    #pragma unroll 1
    for (int i = 0; i < 8; ++i) {
        const float* hb = hmp + (size_t)i * DD;
        float mv[8][3];
        #pragma unroll
        for (int k = 0; k < 8; ++k)
            #pragma unroll
            for (int u = 0; u < 3; ++u)
                mv[k][u] = hb[(size_t)(k * 8) * DD + u * 256];
        float c1v[8], pv[8], b1v[8];
        #pragma unroll
        for (int k = 0; k < 8; ++k) { c1v[k] = sC1[k*8+i]; pv[k] = sP[k*8+i]; b1v[k] = sB1[k*8+i]; }
        #pragma unroll
        for (int u = 0; u < 3; ++u) {
            float x[8];
            #pragma unroll
            for (int k = 0; k < 8; ++k) x[k] = t0[k][u] * c1v[k];
            float mx = fmaxf(fmaxf(fmaxf(x[0], x[1]), fmaxf(x[2], x[3])),
                             fmaxf(fmaxf(x[4], x[5]), fmaxf(x[6], x[7])));
            float es = 0.f;
            #pragma unroll
            for (int k = 0; k < 8; ++k) { x[k] = __expf(x[k] - mx); es += x[k]; }
            float inv = 1.f / es;
            #pragma unroll
            for (int k = 0; k < 8; ++k) {
                vh[k][u]  += (x[k] * inv + pv[k]) * mv[k][u];
                tq1[k][u] += b1v[k] * mv[k][u];
            }
        }
    }
    #pragma unroll
    for (int k = 0; k < 8; ++k) {
        float p2 = 0.f, p1 = 0.f, p0 = 0.f;
        #pragma unroll
        for (int u = 0; u < 3; ++u) {
            sVv[k][u * 256 + tid] = vh[k][u];
            p2 += vh[k][u] * vh[k][u];
            p1 += vh[k][u];
            p0 += t0[k][u] * vh[k][u];
        }
        WRED(p2, k); WRED(p1, 8 + k); WRED(p0, 16 + k);
    }
    __syncthreads();

    // ---- pass 2: u[ji] = M_ji . hv2_j, two rows per iter, batched ----
    #pragma unroll 1
    for (int tt = 0; tt < 8; ++tt) {
        const int ta = wave + tt * 8;
        const int tb = ta + 4;
        const int ja = ta >> 3, jb = tb >> 3;
        const float* Ma = hm + (size_t)ta * DD;
        const float* Mb = hm + (size_t)tb * DD;
        float4 va[3], vb[3];
        #pragma unroll
        for (int c = 0; c < 3; ++c) {
            const int dd = c * 256 + lane * 4;
            va[c] = *reinterpret_cast<const float4*>(Ma + dd);
            vb[c] = *reinterpret_cast<const float4*>(Mb + dd);
        }
        float4 sa[3], sb[3];
        #pragma unroll
        for (int c = 0; c < 3; ++c) {
            const int dd = c * 256 + lane * 4;
            sa[c] = *reinterpret_cast<const float4*>(&sVv[ja][dd]);
            sb[c] = *reinterpret_cast<const float4*>(&sVv[jb][dd]);
        }
        float acca = 0.f, accb = 0.f;
        #pragma unroll
        for (int c = 0; c < 3; ++c) {
            acca += va[c].x*sa[c].x + va[c].y*sa[c].y + va[c].z*sa[c].z + va[c].w*sa[c].w;
            accb += vb[c].x*sb[c].x + vb[c].y*sb[c].y + vb[c].z*sb[c].z + vb[c].w*sb[c].w;
        }
        acca += __shfl_down(acca, 32); acca += __shfl_down(acca, 16);
        acca += __shfl_down(acca, 8);  acca += __shfl_down(acca, 4);
        acca += __shfl_down(acca, 2);  acca += __shfl_down(acca, 1);
        accb += __shfl_down(accb, 32); accb += __shfl_down(accb, 16);
        accb += __shfl_down(accb, 8);  accb += __shfl_down(accb, 4);
        accb += __shfl_down(accb, 2);  accb += __shfl_down(accb, 1);
        if (lane == 0) { sDot[ta] = acca; sDot[tb] = accb; }
    }
    FIN(24);
    __syncthreads();

    // ---- stage 2 (wave 0): p2, c2 ----
    if (tid < 64) {
        const int j = lane >> 3;
        const float n2h2 = rstat[j];               // |hv2|^2
        const float Sh2  = rstat[8 + j];           // sum(hv2)
        const float dqh2 = rstat[16 + j];          // dot(q', hv2)
        const float u = sDot[lane];                // dot(M_ji, hv2_j)
        float s2 = n2h2 / ((1.f + n2h2) * sqrtf(n2h2 + EPSF));
        float c2 = s2 * u;
        sC2[lane] = c2;
        float dotM2 = 0.5f * (dotM1 + c2);
        float w0u = w0 * u; XR3(w0u);              // dot(hv1, hv2)
        float dt1h2 = 0.5f * (dqh2 + s1 * w0u);    // dot(tq1, hv2)
        float Sq2_ = 0.5f * (Sq1 + s2 * Sh2);
        float Sq22 = 0.25f * Sq21 + 0.5f * s2 * dt1h2 + 0.25f * s2 * s2 * n2h2;  // |tq2|^2
        float varq2 = fmaxf(Sq22 - Sq2_ * Sq2_ * (1.f / 768.f), 0.f);
        sP[lane] = tanhf((dotM2 - mu * Sq2_) / (sqrtf(mc2 * varq2) + EPSF));     // p2
    }
    __syncthreads();

    // ---- pass 3 (d-space): final softmax + hv3 + squash + write, batched ----
    #pragma unroll
    for (int k = 0; k < 8; ++k)
        #pragma unroll
        for (int u = 0; u < 3; ++u) vh[k][u] = 0.f;
    #pragma unroll 1
    for (int i = 0; i < 8; ++i) {
        const float* hb = hmp + (size_t)i * DD;
        float mv[8][3];
        #pragma unroll
        for (int k = 0; k < 8; ++k)
            #pragma unroll
            for (int u = 0; u < 3; ++u)
                mv[k][u] = hb[(size_t)(k * 8) * DD + u * 256];
        float c1v[8], c2v[8], pv[8];
        #pragma unroll
        for (int k = 0; k < 8; ++k) { c1v[k] = sC1[k*8+i]; c2v[k] = sC2[k*8+i]; pv[k] = sP[k*8+i]; }
        #pragma unroll
        for (int u = 0; u < 3; ++u) {
            float x[8];
            #pragma unroll
            for (int k = 0; k < 8; ++k) x[k] = t0[k][u] * c1v[k] + tq1[k][u] * c2v[k];
            float mx = fmaxf(fmaxf(fmaxf(x[0], x[1]), fmaxf(x[2], x[3])),
                             fmaxf(fmaxf(x[4], x[5]), fmaxf(x[6], x[7])));
            float es = 0.f;
            #pragma unroll
            for (int k = 0; k < 8; ++k) { x[k] = __expf(x[k] - mx); es += x[k]; }
            float inv = 1.f / es;
            #pragma unroll
            for (int k = 0; k < 8; ++k)
                vh[k][u] += (x[k] * inv + pv[k]) * mv[k][u];
        }
    }
    #pragma unroll
    for (int k = 0; k < 8; ++k) {
        float p2 = vh[k][0]*vh[k][0] + vh[k][1]*vh[k][1] + vh[k][2]*vh[k][2];
        WRED(p2, k);
    }
    __syncthreads();
    FIN(8);
    __syncthreads();
    float* On = out + (size_t)n * JD + tid;
    #pragma unroll
    for (int k = 0; k < 8; ++k) {
        float n2 = rstat[k];
        float sc = n2 / ((1.f + n2) * sqrtf(n2 + EPSF));
        #pragma unroll
        for (int u = 0; u < 3; ++u)
            On[k * DD + u * 256] = vh[k][u] * sc;
    }
#undef WRED
#undef FIN
#undef XR3
}

extern "C" void kernel_launch(void* const* d_in, const int* in_sizes, int n_in,
                              void* d_out, int out_size, void* d_ws, size_t ws_size,
                              hipStream_t stream) {
    const float* m  = (const float*)d_in[0];   // [8,768]
    const float* q  = (const float*)d_in[1];   // [400,768]
    const float* W  = (const float*)d_in[2];   // [1,8,8,768,768]
    const float* b  = (const float*)d_in[3];   // [1,8,8,768]
    const float* Wn = (const float*)d_in[4];   // [768,768]
    float* out = (float*)d_out;
    float* ws  = (float*)d_ws;

    float* H     = ws + OFF_H;
    float* hm    = ws + OFF_HM;
    float* muM   = ws + OFF_MU;
    float* mc2M  = ws + OFF_MC2;
    float* G     = ws + OFF_G;
    float* dmq   = ws + OFF_DMQ;
    float* Sq0v  = ws + OFF_SQ0;
    float* Sq20v = ws + OFF_SQ20;
    unsigned short* A2 = (unsigned short*)(ws + OFF_A2);
    unsigned short* B2 = (unsigned short*)(ws + OFF_B2);

    k_cvt<<<dim3(1944), 256, 0, stream>>>(q, m, Wn, W, A2, B2);
    k_gemm_mfma<<<dim3(96, 4), 256, 0, stream>>>(A2, B2, H);
    k_mid<<<dim3(256), 256, 0, stream>>>(H, b, hm, muM, mc2M, G, dmq, Sq0v, Sq20v);
    k_route2<<<dim3(400), 256, 0, stream>>>(H, hm, muM, mc2M, G, dmq, Sq0v, Sq20v, out);
}

// Round 13
// 124.352 us; speedup vs baseline: 2.1217x; 1.0910x over previous
//
#include <hip/hip_runtime.h>
#include <math.h>

#define DD    768
#define NQ    400
#define NROWS 408          // 400 q rows + 8 m_proj rows
#define JD    6144         // J*D = 8*768
#define WSLICE 4718592     // I*D*E = 8*768*768 (stride between j slices of W)
#define EPSF  1e-8f
#define K2E   1536         // effective GEMM K: hi*hi + lo*hi (hi*lo dropped)
#define K2S   1536         // A stored K (hi|lo)
#define KB2S  768          // B stored K (hi only)

// ---------------- workspace layout (floats) ----------------
#define OFF_H     0                       // [408][6144]
#define OFF_HM    (OFF_H + 408*6144)      // [64][768]  (j*8+i major)
#define OFF_MU    (OFF_HM + 64*768)       // [64]
#define OFF_MC2   (OFF_MU + 64)           // [64]
#define OFF_G     (OFF_MC2 + 64)          // [64][8]  Gram
#define OFF_A2    (OFF_G + 512)           // [512][1536] bf16 (as u16)
#define OFF_B2    (OFF_A2 + 512*K2S/2)    // [6144][768] bf16 (as u16)

#define FOR8(M) M(0) M(1) M(2) M(3) M(4) M(5) M(6) M(7)

typedef __attribute__((ext_vector_type(8))) short short8v;
typedef __attribute__((ext_vector_type(4))) float float4v;

__device__ inline unsigned short f2bf(float x) {
    unsigned u = __float_as_uint(x);
    u += 0x7FFF + ((u >> 16) & 1);
    return (unsigned short)(u >> 16);
}
__device__ inline float bf2f(unsigned short h) {
    return __uint_as_float(((unsigned)h) << 16);
}

// ---------------- kernel 1: pack A'=[hi|lo]; B'=[hi] --------------------------
__global__ __launch_bounds__(256) void k_cvt(const float* __restrict__ q,
                                             const float* __restrict__ m,
                                             const float* __restrict__ Wn,
                                             const float* __restrict__ W,
                                             unsigned short* __restrict__ A2,
                                             unsigned short* __restrict__ B2)
{
    const int bid = blockIdx.x;
    const int tid = threadIdx.x;
    if (bid < 408) {
        const int r = bid;
        unsigned short* dst = A2 + (size_t)r * K2S;
        if (r < NQ) {
            const float* src = q + (size_t)r * DD;
            #pragma unroll
            for (int u0 = 0; u0 < 3; ++u0) {
                const int u = u0 * 256 + tid;
                float x = src[u];
                unsigned short hi = f2bf(x);
                unsigned short lo = f2bf(x - bf2f(hi));
                dst[u] = hi; dst[DD + u] = lo;
            }
        } else {
            const int i = r - NQ;
            float a0 = 0.f, a1 = 0.f, a2 = 0.f;
            #pragma unroll 8
            for (int e = 0; e < DD; ++e) {
                const float mv = m[i*DD + e];
                const float* wr = Wn + (size_t)e * DD;
                a0 += mv * wr[tid];
                a1 += mv * wr[tid + 256];
                a2 += mv * wr[tid + 512];
            }
            #pragma unroll
            for (int u0 = 0; u0 < 3; ++u0) {
                const int u = u0 * 256 + tid;
                float x = (u0 == 0) ? a0 : (u0 == 1) ? a1 : a2;
                unsigned short hi = f2bf(x);
                unsigned short lo = f2bf(x - bf2f(hi));
                dst[u] = hi; dst[DD + u] = lo;
            }
        }
    } else {
        const int r0 = (bid - 408) * 4;
        #pragma unroll
        for (int rr = 0; rr < 4; ++rr) {
            const int rw = r0 + rr;
            const int jj = rw / 768;
            const int d  = rw - jj * 768;
            const float* src = W + (size_t)jj * WSLICE + (size_t)d * DD;
            unsigned short* dst = B2 + (size_t)rw * KB2S;
            #pragma unroll
            for (int u0 = 0; u0 < 3; ++u0) {
                const int u = u0 * 256 + tid;
                dst[u] = f2bf(src[u]);
            }
        }
    }
}

// ---------------- kernel 2: MFMA GEMM, BM=128 x BN=64, 2-phase dbuf -----------
// Effective K = 1536: k<768: Ahi*Bhi; 768..1535: Alo*Bhi.
__global__ __launch_bounds__(256) void k_gemm_mfma(const unsigned short* __restrict__ A2,
                                                   const unsigned short* __restrict__ B2,
                                                   float* __restrict__ H)
{
    __shared__ __align__(16) unsigned short lds[2][12288];  // A:[0,8192) B:[8192,12288)
    const int tid = threadIdx.x;
    const int wv  = tid >> 6;
    const int ln  = tid & 63;
    const int c0  = blockIdx.x * 64;
    const int m0  = blockIdx.y * 128;
    const int wm  = (wv >> 1) * 64;
    const int wn  = (wv & 1) * 32;
    const unsigned short* Ap = A2 + (size_t)m0 * K2S;
    const unsigned short* Bp = B2 + (size_t)c0 * KB2S;

    float4v acc[4][2];
    #pragma unroll
    for (int a = 0; a < 4; ++a)
        #pragma unroll
        for (int b = 0; b < 2; ++b)
            acc[a][b] = (float4v){0.f, 0.f, 0.f, 0.f};

#define STAGE(buf, ka, kb) {                                                      \
    _Pragma("unroll")                                                             \
    for (int qq = 0; qq < 4; ++qq) {                                              \
        const int idx = (qq << 8) + tid;                                          \
        const int row = idx >> 3;                                                 \
        const int ce  = ((idx & 7) ^ (row & 7)) << 3;                             \
        __builtin_amdgcn_global_load_lds(                                         \
            (const __attribute__((address_space(1))) void*)(Ap + (size_t)row * K2S + (ka) + ce), \
            (__attribute__((address_space(3))) void*)(&lds[buf][idx * 8]), 16, 0, 0);            \
    }                                                                             \
    _Pragma("unroll")                                                             \
    for (int qq = 0; qq < 2; ++qq) {                                              \
        const int idx = (qq << 8) + tid;                                          \
        const int row = idx >> 3;                                                 \
        const int ce  = ((idx & 7) ^ (row & 7)) << 3;                             \
        __builtin_amdgcn_global_load_lds(                                         \
            (const __attribute__((address_space(1))) void*)(Bp + (size_t)row * KB2S + (kb) + ce), \
            (__attribute__((address_space(3))) void*)(&lds[buf][8192 + idx * 8]), 16, 0, 0);     \
    } }

#define COMPUTE(buf) { _Pragma("unroll")                                          \
    for (int s = 0; s < 2; ++s) {                                                 \
        short8v af[4], bf[2];                                                     \
        _Pragma("unroll")                                                         \
        for (int mi = 0; mi < 4; ++mi) {                                          \
            const int row = wm + mi * 16 + (ln & 15);                             \
            const int off = row * 64 + ((s * 32 + ((ln >> 4) * 8)) ^ ((row & 7) << 3)); \
            af[mi] = *reinterpret_cast<const short8v*>(&lds[buf][off]);           \
        }                                                                         \
        _Pragma("unroll")                                                         \
        for (int ni = 0; ni < 2; ++ni) {                                          \
            const int row = wn + ni * 16 + (ln & 15);                             \
            const int off = row * 64 + ((s * 32 + ((ln >> 4) * 8)) ^ ((row & 7) << 3)); \
            bf[ni] = *reinterpret_cast<const short8v*>(&lds[buf][8192 + off]);    \
        }                                                                         \
        _Pragma("unroll")                                                         \
        for (int mi = 0; mi < 4; ++mi)                                            \
            _Pragma("unroll")                                                     \
            for (int ni = 0; ni < 2; ++ni)                                        \
                acc[mi][ni] = __builtin_amdgcn_mfma_f32_16x16x32_bf16(af[mi], bf[ni], acc[mi][ni], 0, 0, 0); \
    } }

    STAGE(0, 0, 0);
    __syncthreads();
    int cur = 0;
    for (int k0 = 64; k0 < K2E; k0 += 64) {
        const int kb = (k0 < 768) ? k0 : k0 - 768;     // A: hi|lo ; B: hi reused
        STAGE(cur ^ 1, k0, kb);
        COMPUTE(cur);
        __syncthreads();
        cur ^= 1;
    }
    COMPUTE(cur);
#undef STAGE
#undef COMPUTE

    #pragma unroll
    for (int mi = 0; mi < 4; ++mi) {
        #pragma unroll
        for (int r = 0; r < 4; ++r) {
            const int gr = m0 + wm + mi * 16 + (ln >> 4) * 4 + r;
            if (gr < NROWS) {
                #pragma unroll
                for (int ni = 0; ni < 2; ++ni)
                    H[(size_t)gr * JD + c0 + wn + ni * 16 + (ln & 15)] = acc[mi][ni][r];
            }
        }
    }
}

// ---------------- kernel 3: merged prep / gram --------------------------------
__global__ __launch_bounds__(256) void k_mid(const float* __restrict__ H,
                                             const float* __restrict__ b,
                                             float* __restrict__ hm,
                                             float* __restrict__ muM,
                                             float* __restrict__ mc2M,
                                             float* __restrict__ G)
{
    const int bid = blockIdx.x;
    const int tid = threadIdx.x;
    const int lane = tid & 63, wave = tid >> 6;
    __shared__ float scr[8][4];
    __shared__ float smu;

    if (bid < 64) {
        // ---------------- prep ----------------
        const int ji = bid;
        const int j = ji >> 3, i = ji & 7;
        float vals[3];
        float s = 0.f;
        #pragma unroll
        for (int u = 0; u < 3; ++u) {
            const int d = u * 256 + tid;
            float x = H[(size_t)(NQ + i) * JD + j * DD + d] + b[(size_t)ji * DD + d];
            hm[(size_t)ji * DD + d] = x;
            vals[u] = x;
            s += x;
        }
        #pragma unroll
        for (int off = 32; off; off >>= 1) s += __shfl_down(s, off);
        if (lane == 0) scr[0][wave] = s;
        __syncthreads();
        if (tid == 0) smu = (scr[0][0] + scr[0][1] + scr[0][2] + scr[0][3]) * (1.f / 768.f);
        __syncthreads();
        const float mu = smu;
        float s2 = 0.f;
        #pragma unroll
        for (int u = 0; u < 3; ++u) { float c = vals[u] - mu; s2 += c * c; }
        __syncthreads();
        #pragma unroll
        for (int off = 32; off; off >>= 1) s2 += __shfl_down(s2, off);
        if (lane == 0) scr[0][wave] = s2;
        __syncthreads();
        if (tid == 0) { muM[ji] = mu; mc2M[ji] = scr[0][0] + scr[0][1] + scr[0][2] + scr[0][3]; }
    } else {
        // ---------------- gram ----------------
        const int ji = bid - 64;
        const int j = ji >> 3, i = ji & 7;
        const float* Hj = H + j * DD;
        const float* bj = b + (size_t)(j * 8) * DD;
        const float a0 = Hj[(size_t)(NQ + i) * JD + tid]       + bj[(size_t)i * DD + tid];
        const float a1 = Hj[(size_t)(NQ + i) * JD + 256 + tid] + bj[(size_t)i * DD + 256 + tid];
        const float a2 = Hj[(size_t)(NQ + i) * JD + 512 + tid] + bj[(size_t)i * DD + 512 + tid];
#define GDOT(k) { const float* Hp = Hj + (size_t)(NQ + k) * JD + tid;            \
        const float* bp = bj + (size_t)k * DD + tid;                             \
        float acc = a0*(Hp[0]+bp[0]) + a1*(Hp[256]+bp[256]) + a2*(Hp[512]+bp[512]); \
        acc += __shfl_down(acc, 32); acc += __shfl_down(acc, 16);                \
        acc += __shfl_down(acc, 8);  acc += __shfl_down(acc, 4);                 \
        acc += __shfl_down(acc, 2);  acc += __shfl_down(acc, 1);                 \
        if (lane == 0) scr[k][wave] = acc; }
        FOR8(GDOT)
#undef GDOT
        __syncthreads();
        if (tid < 8) G[ji*8 + tid] = scr[tid][0] + scr[tid][1] + scr[tid][2] + scr[tid][3];
    }
}

// ---------------- kernel 4: fused routing, 256 thr x 3 d, inline dots ---------
__global__ __launch_bounds__(256) void k_route2(const float* __restrict__ H,
                                                const float* __restrict__ hm,
                                                const float* __restrict__ muM,
                                                const float* __restrict__ mc2M,
                                                const float* __restrict__ G,
                                                float* __restrict__ out)
{
    const int n = blockIdx.x;
    const int tid = threadIdx.x;                  // d base; thread owns d = u*256+tid
    const int lane = tid & 63, wave = tid >> 6;   // 4 waves
    __shared__ __align__(16) float sVv[8][768];
    __shared__ float scr[24][4];
    __shared__ float rstat[24];
    __shared__ float sDot[64];
    __shared__ float sP[64], sC1[64], sC2[64], sB1[64];

#define WRED(val, idx) { float _v = (val);                           \
    _v += __shfl_down(_v, 32); _v += __shfl_down(_v, 16);            \
    _v += __shfl_down(_v, 8);  _v += __shfl_down(_v, 4);             \
    _v += __shfl_down(_v, 2);  _v += __shfl_down(_v, 1);             \
    if (lane == 0) scr[(idx)][wave] = _v; }

#define FIN(nv) { if (tid < (nv))                                    \
    rstat[tid] = scr[tid][0] + scr[tid][1] + scr[tid][2] + scr[tid][3]; }

// batched 2-rows-per-iter dot of hm rows against sVv (64 rows over 4 waves)
#define DOT2() _Pragma("unroll 1")                                    \
    for (int tt = 0; tt < 8; ++tt) {                                  \
        const int ta = wave + tt * 8;                                 \
        const int tb = ta + 4;                                        \
        const int ja = ta >> 3, jb = tb >> 3;                         \
        const float* Ma = hm + (size_t)ta * DD;                       \
        const float* Mb = hm + (size_t)tb * DD;                       \
        float4 va[3], vb[3], sa[3], sb[3];                            \
        _Pragma("unroll")                                             \
        for (int c = 0; c < 3; ++c) {                                 \
            const int dd = c * 256 + lane * 4;                        \
            va[c] = *reinterpret_cast<const float4*>(Ma + dd);        \
            vb[c] = *reinterpret_cast<const float4*>(Mb + dd);        \
            sa[c] = *reinterpret_cast<const float4*>(&sVv[ja][dd]);   \
            sb[c] = *reinterpret_cast<const float4*>(&sVv[jb][dd]);   \
        }                                                             \
        float acca = 0.f, accb = 0.f;                                 \
        _Pragma("unroll")                                             \
        for (int c = 0; c < 3; ++c) {                                 \
            acca += va[c].x*sa[c].x + va[c].y*sa[c].y + va[c].z*sa[c].z + va[c].w*sa[c].w; \
            accb += vb[c].x*sb[c].x + vb[c].y*sb[c].y + vb[c].z*sb[c].z + vb[c].w*sb[c].w; \
        }                                                             \
        acca += __shfl_down(acca, 32); acca += __shfl_down(acca, 16); \
        acca += __shfl_down(acca, 8);  acca += __shfl_down(acca, 4);  \
        acca += __shfl_down(acca, 2);  acca += __shfl_down(acca, 1);  \
        accb += __shfl_down(accb, 32); accb += __shfl_down(accb, 16); \
        accb += __shfl_down(accb, 8);  accb += __shfl_down(accb, 4);  \
        accb += __shfl_down(accb, 2);  accb += __shfl_down(accb, 1);  \
        if (lane == 0) { sDot[ta] = acca; sDot[tb] = accb; }          \
    }

#define XR3(v) { v += __shfl_xor(v, 1); v += __shfl_xor(v, 2); v += __shfl_xor(v, 4); }

    // ---- phase A: load tq0, stage, stats + inline dots (M . tq0) ----
    const float* Hn = H + (size_t)n * JD + tid;
    const float* hmp = hm + tid;
    float t0[8][3], tq1[8][3], vh[8][3];
    #pragma unroll
    for (int k = 0; k < 8; ++k) {
        float s = 0.f, s2 = 0.f;
        #pragma unroll
        for (int u = 0; u < 3; ++u) {
            t0[k][u] = Hn[k * DD + u * 256];
            sVv[k][u * 256 + tid] = t0[k][u];
            s += t0[k][u]; s2 += t0[k][u] * t0[k][u];
        }
        WRED(s, k); WRED(s2, 8 + k);
    }
    __syncthreads();
    DOT2();                                        // sDot = M . tq0
    FIN(16);                                       // rstat[0..7]=Sq, [8..15]=Sq2
    __syncthreads();

    // ---- stage 0 (wave 0): coefficient-space routing iteration 1 ----
    float w0 = 0.f, s1 = 0.f, dotM1 = 0.f, Sq1 = 0.f, Sq21 = 0.f, mu = 0.f, mc2 = 0.f;
    if (tid < 64) {
        const int j = lane >> 3;
        mu  = muM[lane];
        mc2 = mc2M[lane];
        const float smR = 768.f * mu;              // sum of M row
        const float dq  = sDot[lane];
        const float Sq  = rstat[j];
        const float Sq2v = rstat[8 + j];
        {
            float num  = dq - mu * Sq;
            float varq = fmaxf(Sq2v - Sq * Sq * (1.f / 768.f), 0.f);
            float den  = sqrtf(mc2 * varq) + EPSF;
            w0 = tanhf(num / den) + 0.125f;        // w0 = 1/8 + p0
        }
        const float* Gr = G + lane * 8;
        const int base = lane & ~7;
        float gw = 0.f;
        #pragma unroll
        for (int ii = 0; ii < 8; ++ii) gw += Gr[ii] * __shfl(w0, base + ii);
        float n2h1 = w0 * gw;  XR3(n2h1);          // |hv1|^2
        float dqh1 = w0 * dq;  XR3(dqh1);          // dot(q', hv1)
        float Sh1  = w0 * smR; XR3(Sh1);           // sum(hv1)
        s1 = n2h1 / ((1.f + n2h1) * sqrtf(n2h1 + EPSF));
        float c1 = s1 * gw;
        sC1[lane] = c1;
        sB1[lane] = 0.5f * s1 * w0;
        dotM1 = 0.5f * (dq + c1);
        Sq1   = 0.5f * (Sq + s1 * Sh1);
        Sq21  = 0.25f * (Sq2v + 2.f * s1 * dqh1 + s1 * s1 * n2h1);   // |tq1|^2
        float varq1 = fmaxf(Sq21 - Sq1 * Sq1 * (1.f / 768.f), 0.f);
        sP[lane] = tanhf((dotM1 - mu * Sq1) / (sqrtf(mc2 * varq1) + EPSF));  // p1
    }
    __syncthreads();

    // ---- pass 1 (d-space): hv2 + tq1 reconstruction, batched loads ----
    #pragma unroll
    for (int k = 0; k < 8; ++k)
        #pragma unroll
        for (int u = 0; u < 3; ++u) {
            tq1[k][u] = 0.5f * t0[k][u];
            vh[k][u] = 0.f;
        }
    #pragma unroll 1
    for (int i = 0; i < 8; ++i) {
        const float* hb = hmp + (size_t)i * DD;
        float mv[8][3];
        #pragma unroll
        for (int k = 0; k < 8; ++k)
            #pragma unroll
            for (int u = 0; u < 3; ++u)
                mv[k][u] = hb[(size_t)(k * 8) * DD + u * 256];
        float c1v[8], pv[8], b1v[8];
        #pragma unroll
        for (int k = 0; k < 8; ++k) { c1v[k] = sC1[k*8+i]; pv[k] = sP[k*8+i]; b1v[k] = sB1[k*8+i]; }
        #pragma unroll
        for (int u = 0; u < 3; ++u) {
            float x[8];
            #pragma unroll
            for (int k = 0; k < 8; ++k) x[k] = t0[k][u] * c1v[k];
            float mx = fmaxf(fmaxf(fmaxf(x[0], x[1]), fmaxf(x[2], x[3])),
                             fmaxf(fmaxf(x[4], x[5]), fmaxf(x[6], x[7])));
            float es = 0.f;
            #pragma unroll
            for (int k = 0; k < 8; ++k) { x[k] = __expf(x[k] - mx); es += x[k]; }
            float inv = 1.f / es;
            #pragma unroll
            for (int k = 0; k < 8; ++k) {
                vh[k][u]  += (x[k] * inv + pv[k]) * mv[k][u];
                tq1[k][u] += b1v[k] * mv[k][u];
            }
        }
    }
    __syncthreads();                               // sVv (tq0) fully consumed
    #pragma unroll
    for (int k = 0; k < 8; ++k) {
        float p2 = 0.f, p1 = 0.f, p0 = 0.f;
        #pragma unroll
        for (int u = 0; u < 3; ++u) {
            sVv[k][u * 256 + tid] = vh[k][u];
            p2 += vh[k][u] * vh[k][u];
            p1 += vh[k][u];
            p0 += t0[k][u] * vh[k][u];
        }
        WRED(p2, k); WRED(p1, 8 + k); WRED(p0, 16 + k);
    }
    __syncthreads();

    // ---- pass 2: u[ji] = M_ji . hv2_j ----
    DOT2();
    FIN(24);
    __syncthreads();

    // ---- stage 2 (wave 0): p2, c2 ----
    if (tid < 64) {
        const int j = lane >> 3;
        const float n2h2 = rstat[j];               // |hv2|^2
        const float Sh2  = rstat[8 + j];           // sum(hv2)
        const float dqh2 = rstat[16 + j];          // dot(q', hv2)
        const float u = sDot[lane];                // dot(M_ji, hv2_j)
        float s2 = n2h2 / ((1.f + n2h2) * sqrtf(n2h2 + EPSF));
        float c2 = s2 * u;
        sC2[lane] = c2;
        float dotM2 = 0.5f * (dotM1 + c2);
        float w0u = w0 * u; XR3(w0u);              // dot(hv1, hv2)
        float dt1h2 = 0.5f * (dqh2 + s1 * w0u);    // dot(tq1, hv2)
        float Sq2_ = 0.5f * (Sq1 + s2 * Sh2);
        float Sq22 = 0.25f * Sq21 + 0.5f * s2 * dt1h2 + 0.25f * s2 * s2 * n2h2;  // |tq2|^2
        float varq2 = fmaxf(Sq22 - Sq2_ * Sq2_ * (1.f / 768.f), 0.f);
        sP[lane] = tanhf((dotM2 - mu * Sq2_) / (sqrtf(mc2 * varq2) + EPSF));     // p2
    }
    __syncthreads();

    // ---- pass 3 (d-space): final softmax + hv3 + squash + write, batched ----
    #pragma unroll
    for (int k = 0; k < 8; ++k)
        #pragma unroll
        for (int u = 0; u < 3; ++u) vh[k][u] = 0.f;
    #pragma unroll 1
    for (int i = 0; i < 8; ++i) {
        const float* hb = hmp + (size_t)i * DD;
        float mv[8][3];
        #pragma unroll
        for (int k = 0; k < 8; ++k)
            #pragma unroll
            for (int u = 0; u < 3; ++u)
                mv[k][u] = hb[(size_t)(k * 8) * DD + u * 256];
        float c1v[8], c2v[8], pv[8];
        #pragma unroll
        for (int k = 0; k < 8; ++k) { c1v[k] = sC1[k*8+i]; c2v[k] = sC2[k*8+i]; pv[k] = sP[k*8+i]; }
        #pragma unroll
        for (int u = 0; u < 3; ++u) {
            float x[8];
            #pragma unroll
            for (int k = 0; k < 8; ++k) x[k] = t0[k][u] * c1v[k] + tq1[k][u] * c2v[k];
            float mx = fmaxf(fmaxf(fmaxf(x[0], x[1]), fmaxf(x[2], x[3])),
                             fmaxf(fmaxf(x[4], x[5]), fmaxf(x[6], x[7])));
            float es = 0.f;
            #pragma unroll
            for (int k = 0; k < 8; ++k) { x[k] = __expf(x[k] - mx); es += x[k]; }
            float inv = 1.f / es;
            #pragma unroll
            for (int k = 0; k < 8; ++k)
                vh[k][u] += (x[k] * inv + pv[k]) * mv[k][u];
        }
    }
    #pragma unroll
    for (int k = 0; k < 8; ++k) {
        float p2 = vh[k][0]*vh[k][0] + vh[k][1]*vh[k][1] + vh[k][2]*vh[k][2];
        WRED(p2, k);
    }
    __syncthreads();
    FIN(8);
    __syncthreads();
    float* On = out + (size_t)n * JD + tid;
    #pragma unroll
    for (int k = 0; k < 8; ++k) {
        float n2 = rstat[k];
        float sc = n2 / ((1.f + n2) * sqrtf(n2 + EPSF));
        #pragma unroll
        for (int u = 0; u < 3; ++u)
            On[k * DD + u * 256] = vh[k][u] * sc;
    }
#undef WRED
#undef FIN
#undef DOT2
#undef XR3
}

extern "C" void kernel_launch(void* const* d_in, const int* in_sizes, int n_in,
                              void* d_out, int out_size, void* d_ws, size_t ws_size,
                              hipStream_t stream) {
    const float* m  = (const float*)d_in[0];   // [8,768]
    const float* q  = (const float*)d_in[1];   // [400,768]
    const float* W  = (const float*)d_in[2];   // [1,8,8,768,768]
    const float* b  = (const float*)d_in[3];   // [1,8,8,768]
    const float* Wn = (const float*)d_in[4];   // [768,768]
    float* out = (float*)d_out;
    float* ws  = (float*)d_ws;

    float* H     = ws + OFF_H;
    float* hm    = ws + OFF_HM;
    float* muM   = ws + OFF_MU;
    float* mc2M  = ws + OFF_MC2;
    float* G     = ws + OFF_G;
    unsigned short* A2 = (unsigned short*)(ws + OFF_A2);
    unsigned short* B2 = (unsigned short*)(ws + OFF_B2);

    k_cvt<<<dim3(1944), 256, 0, stream>>>(q, m, Wn, W, A2, B2);
    k_gemm_mfma<<<dim3(96, 4), 256, 0, stream>>>(A2, B2, H);
    k_mid<<<dim3(128), 256, 0, stream>>>(H, b, hm, muM, mc2M, G);
    k_route2<<<dim3(400), 256, 0, stream>>>(H, hm, muM, mc2M, G, out);
}